// Round 2
// baseline (2591.020 us; speedup 1.0000x reference)
//
#include <hip/hip_runtime.h>

#define N_ENT 50000
#define N_EDG 600000
#define CH 128
#define LEAKY 0.01f

// ---------------- counts (in-degree of head) --------------------------------
__global__ __launch_bounds__(256) void count_kernel(const int* __restrict__ head,
                                                    float* __restrict__ counts) {
    int e = blockIdx.x * 256 + threadIdx.x;
    if (e < N_EDG) atomicAdd(&counts[head[e]], 1.0f);
}

// ---------------- scatter: agg[head] += res[tail] * weight[etype] ----------
// 32 threads per edge, 4 channels each (float4 gather, 4 atomics)
__global__ __launch_bounds__(256) void scatter_kernel(
    const float* __restrict__ res, const int* __restrict__ head,
    const int* __restrict__ tail, const int* __restrict__ etype,
    const float* __restrict__ weight, float* __restrict__ agg) {
    long long gid = (long long)blockIdx.x * 256 + threadIdx.x;
    int e = (int)(gid >> 5);
    int c = (int)(gid & 31) * 4;
    if (e >= N_EDG) return;
    int h = head[e];
    int t = tail[e];
    int r = etype[e];
    const float4 rv = *(const float4*)&res[(long long)t * CH + c];
    const float4 wv = *(const float4*)&weight[r * CH + c];
    float* dst = &agg[(long long)h * CH + c];
    atomicAdd(dst + 0, rv.x * wv.x);
    atomicAdd(dst + 1, rv.y * wv.y);
    atomicAdd(dst + 2, rv.z * wv.z);
    atomicAdd(dst + 3, rv.w * wv.w);
}

// ---------------- normalize: agg = (agg/denom) / max(||agg/denom||, eps) ---
// one wave per row, 2 channels per lane
__global__ __launch_bounds__(256) void normalize_kernel(float* __restrict__ agg,
                                                        const float* __restrict__ counts) {
    int row = blockIdx.x * 4 + (threadIdx.x >> 6);
    int lane = threadIdx.x & 63;
    float2 v = *(float2*)&agg[(long long)row * CH + lane * 2];
    float d = fmaxf(counts[row], 1.0f);
    v.x /= d;
    v.y /= d;
    float ss = v.x * v.x + v.y * v.y;
#pragma unroll
    for (int off = 32; off >= 1; off >>= 1) ss += __shfl_xor(ss, off);
    float inv = 1.0f / fmaxf(sqrtf(ss), 1e-12f);
    v.x *= inv;
    v.y *= inv;
    *(float2*)&agg[(long long)row * CH + lane * 2] = v;
}

// ---------------- fused dual-GEMM + leaky + add ------------------------------
// out[n][j] = leaky( sum_k (res+agg)[n][k]*W1[j][k] + b1[j] )
//           + leaky( sum_k res[n][k]*W2[j][k] + agg[n][k]*W2[j][128+k] + b2[j] )
// Block: 256 threads = (j = tid&127, row-group rg = tid>>7), 8 rows per block.
__global__ __launch_bounds__(256) void gemm_fused(
    const float* __restrict__ resp, const float* __restrict__ aggp,
    const float* __restrict__ W1, const float* __restrict__ b1,
    const float* __restrict__ W2, const float* __restrict__ b2,
    float* __restrict__ outp) {
    __shared__ float rs[8][CH];
    __shared__ float as_[8][CH];
    __shared__ float w1t[32][129];
    __shared__ float wat[32][129];
    __shared__ float wbt[32][129];

    const int tid = threadIdx.x;
    const int j = tid & 127;
    const int rg = tid >> 7;  // 0..1
    const int row0 = blockIdx.x * 8;

    // stage the 8 x-rows (res, agg)
    {
        int r = tid >> 5;           // 0..7
        int c = (tid & 31) * 4;     // 0..124
        long long src = (long long)(row0 + r) * CH + c;
        *(float4*)&rs[r][c] = *(const float4*)&resp[src];
        *(float4*)&as_[r][c] = *(const float4*)&aggp[src];
    }

    float acc1[4] = {0.f, 0.f, 0.f, 0.f};
    float acc2[4] = {0.f, 0.f, 0.f, 0.f};

    for (int k0 = 0; k0 < CH; k0 += 32) {
        __syncthreads();  // protects x-stage (iter 0) and prior tile reads
        {
            int k = tid & 31;
            int jb = tid >> 5;  // 0..7
#pragma unroll
            for (int it = 0; it < 16; ++it) {
                int jj = jb + it * 8;
                w1t[k][jj] = W1[jj * CH + k0 + k];
                wat[k][jj] = W2[jj * 2 * CH + k0 + k];
                wbt[k][jj] = W2[jj * 2 * CH + CH + k0 + k];
            }
        }
        __syncthreads();
#pragma unroll
        for (int kk = 0; kk < 32; ++kk) {
            float w1 = w1t[kk][j];
            float wa = wat[kk][j];
            float wb = wbt[kk][j];
#pragma unroll
            for (int r = 0; r < 4; ++r) {
                float rv = rs[rg * 4 + r][k0 + kk];
                float av = as_[rg * 4 + r][k0 + kk];
                acc1[r] = fmaf(rv, w1, acc1[r]);
                acc1[r] = fmaf(av, w1, acc1[r]);
                acc2[r] = fmaf(rv, wa, acc2[r]);
                acc2[r] = fmaf(av, wb, acc2[r]);
            }
        }
    }

    float bb1 = b1[j];
    float bb2 = b2[j];
#pragma unroll
    for (int r = 0; r < 4; ++r) {
        long long grow = row0 + rg * 4 + r;
        float e1 = acc1[r] + bb1;
        e1 = e1 >= 0.f ? e1 : LEAKY * e1;
        float e2 = acc2[r] + bb2;
        e2 = e2 >= 0.f ? e2 : LEAKY * e2;
        outp[grow * CH + j] = e1 + e2;
    }
}

// ---------------- copy weight to second output ------------------------------
__global__ __launch_bounds__(256) void copyw_kernel(const float* __restrict__ w,
                                                    float* __restrict__ out) {
    int i = blockIdx.x * 256 + threadIdx.x;
    if (i < 32 * CH) out[i] = w[i];
}

extern "C" void kernel_launch(void* const* d_in, const int* in_sizes, int n_in,
                              void* d_out, int out_size, void* d_ws, size_t ws_size,
                              hipStream_t stream) {
    const float* emb = (const float*)d_in[0];
    const int* eidx = (const int*)d_in[1];     // int64 in reference -> int32 here
    const int* etype = (const int*)d_in[2];    // int64 in reference -> int32 here
    const float* weight = (const float*)d_in[3];
    const float* W1w = (const float*)d_in[4];
    const float* W1b = (const float*)d_in[5];
    const float* W2w = (const float*)d_in[6];
    const float* W2b = (const float*)d_in[7];

    float* out = (float*)d_out;
    float* res_out = out;                         // [N_ENT][CH]
    float* wout = out + (size_t)N_ENT * CH;       // [32][CH]

    float* agg = (float*)d_ws;                    // [N_ENT][CH]
    float* counts = agg + (size_t)N_ENT * CH;     // [N_ENT]

    const int* head = eidx;
    const int* tail = eidx + N_EDG;

    hipMemsetAsync(counts, 0, N_ENT * sizeof(float), stream);
    count_kernel<<<(N_EDG + 255) / 256, 256, 0, stream>>>(head, counts);

    const float* res_in = emb;
    for (int hop = 0; hop < 2; ++hop) {
        hipMemsetAsync(agg, 0, (size_t)N_ENT * CH * sizeof(float), stream);
        scatter_kernel<<<(N_EDG * 32) / 256, 256, 0, stream>>>(res_in, head, tail, etype,
                                                               weight, agg);
        normalize_kernel<<<N_ENT / 4, 256, 0, stream>>>(agg, counts);
        gemm_fused<<<N_ENT / 8, 256, 0, stream>>>(
            res_in, agg, W1w + hop * CH * CH, W1b + hop * CH,
            W2w + hop * 2 * CH * CH, W2b + hop * CH, res_out);
        res_in = res_out;
    }
    copyw_kernel<<<16, 256, 0, stream>>>(weight, wout);
}

// Round 3
// 676.453 us; speedup vs baseline: 3.8303x; 3.8303x over previous
//
#include <hip/hip_runtime.h>

#define N_ENT 50000
#define N_EDG 600000
#define CH 128
#define LEAKY 0.01f
#define NB_SCAN 49  // ceil(50000/1024)

// ---------------- CSR build step 1: in-degree counts ------------------------
__global__ __launch_bounds__(256) void count_kernel(const int* __restrict__ head,
                                                    int* __restrict__ counts) {
    int e = blockIdx.x * 256 + threadIdx.x;
    if (e < N_EDG) atomicAdd(&counts[head[e]], 1);
}

// ---------------- CSR step 2a: per-1024-chunk exclusive scan ----------------
__global__ __launch_bounds__(256) void scan_block(const int* __restrict__ counts,
                                                  int* __restrict__ offs,
                                                  int* __restrict__ bsum) {
    __shared__ int s[256];
    int t = threadIdx.x;
    int base = blockIdx.x * 1024 + t * 4;
    int v[4];
#pragma unroll
    for (int i = 0; i < 4; ++i) {
        int idx = base + i;
        v[i] = (idx < N_ENT) ? counts[idx] : 0;
    }
    int tot = v[0] + v[1] + v[2] + v[3];
    s[t] = tot;
    for (int off = 1; off < 256; off <<= 1) {
        __syncthreads();
        int x = (t >= off) ? s[t - off] : 0;
        __syncthreads();
        s[t] += x;
    }
    int run = s[t] - tot;  // exclusive prefix of this thread's quad
#pragma unroll
    for (int i = 0; i < 4; ++i) {
        if (base + i < N_ENT) offs[base + i] = run;
        run += v[i];
    }
    if (t == 255) bsum[blockIdx.x] = s[255];
}

// ---------------- CSR step 2b: scan the 49 chunk totals ----------------------
__global__ __launch_bounds__(64) void scan_tops(int* __restrict__ bsum) {
    int lane = threadIdx.x;
    int v = (lane < NB_SCAN) ? bsum[lane] : 0;
    int orig = v;
#pragma unroll
    for (int off = 1; off < 64; off <<= 1) {
        int x = __shfl_up(v, off);
        if (lane >= off) v += x;
    }
    if (lane < NB_SCAN) bsum[lane] = v - orig;  // exclusive
}

// ---------------- CSR step 2c: add chunk base, init cursors ------------------
__global__ __launch_bounds__(256) void add_base(int* __restrict__ offs,
                                                int* __restrict__ cursors,
                                                const int* __restrict__ bsum) {
    int t = threadIdx.x;
    int base = blockIdx.x * 1024 + t * 4;
    int b = bsum[blockIdx.x];
#pragma unroll
    for (int i = 0; i < 4; ++i) {
        int idx = base + i;
        if (idx < N_ENT) {
            int o = offs[idx] + b;
            offs[idx] = o;
            cursors[idx] = o;
        }
    }
    if (blockIdx.x == 0 && t == 0) offs[N_ENT] = N_EDG;
}

// ---------------- CSR step 3: fill packed edge payloads ----------------------
__global__ __launch_bounds__(256) void fill_kernel(const int* __restrict__ head,
                                                   const int* __restrict__ tail,
                                                   const int* __restrict__ etype,
                                                   int* __restrict__ cursors,
                                                   int* __restrict__ packed) {
    int e = blockIdx.x * 256 + threadIdx.x;
    if (e >= N_EDG) return;
    int h = head[e];
    int pos = atomicAdd(&cursors[h], 1);
    packed[pos] = tail[e] | (etype[e] << 20);
}

// ---------------- aggregate + mean + L2-normalize (fused) --------------------
// one wave per head row; lane owns channels [2*lane, 2*lane+1]
__global__ __launch_bounds__(256) void agg_kernel(const float* __restrict__ res,
                                                  const int* __restrict__ offs,
                                                  const int* __restrict__ packed,
                                                  const float* __restrict__ weight,
                                                  float* __restrict__ agg) {
    __shared__ float ws[32 * CH];  // 16 KB relation weights
    int tid = threadIdx.x;
#pragma unroll
    for (int i = 0; i < 4; ++i)
        *(float4*)&ws[i * 1024 + tid * 4] = *(const float4*)&weight[i * 1024 + tid * 4];
    __syncthreads();

    int w = tid >> 6;
    int lane = tid & 63;
    int row = blockIdx.x * 4 + w;
    int beg = offs[row], end = offs[row + 1];

    float2 acc = {0.f, 0.f};
    for (int cb = beg; cb < end; cb += 64) {
        int n = min(64, end - cb);
        int myp = (cb + lane < end) ? packed[cb + lane] : 0;
        for (int i = 0; i < n; ++i) {
            int p = __shfl(myp, i);
            int t = p & 0xFFFFF;
            int r = p >> 20;
            float2 rv = *(const float2*)&res[(long long)t * CH + lane * 2];
            float2 wv = *(const float2*)&ws[r * CH + lane * 2];
            acc.x = fmaf(rv.x, wv.x, acc.x);
            acc.y = fmaf(rv.y, wv.y, acc.y);
        }
    }
    float d = fmaxf((float)(end - beg), 1.f);
    acc.x /= d;
    acc.y /= d;
    float ss = acc.x * acc.x + acc.y * acc.y;
#pragma unroll
    for (int off = 32; off >= 1; off >>= 1) ss += __shfl_xor(ss, off);
    float inv = 1.0f / fmaxf(sqrtf(ss), 1e-12f);
    float2 o = {acc.x * inv, acc.y * inv};
    *(float2*)&agg[(long long)row * CH + lane * 2] = o;
}

// ---------------- fused dual-GEMM + leaky + add ------------------------------
__global__ __launch_bounds__(256) void gemm_fused(
    const float* __restrict__ resp, const float* __restrict__ aggp,
    const float* __restrict__ W1, const float* __restrict__ b1,
    const float* __restrict__ W2, const float* __restrict__ b2,
    float* __restrict__ outp) {
    __shared__ float rs[8][CH];
    __shared__ float as_[8][CH];
    __shared__ float w1t[32][129];
    __shared__ float wat[32][129];
    __shared__ float wbt[32][129];

    const int tid = threadIdx.x;
    const int j = tid & 127;
    const int rg = tid >> 7;
    const int row0 = blockIdx.x * 8;

    {
        int r = tid >> 5;
        int c = (tid & 31) * 4;
        long long src = (long long)(row0 + r) * CH + c;
        *(float4*)&rs[r][c] = *(const float4*)&resp[src];
        *(float4*)&as_[r][c] = *(const float4*)&aggp[src];
    }

    float acc1[4] = {0.f, 0.f, 0.f, 0.f};
    float acc2[4] = {0.f, 0.f, 0.f, 0.f};

    for (int k0 = 0; k0 < CH; k0 += 32) {
        __syncthreads();
        {
            int k = tid & 31;
            int jb = tid >> 5;
#pragma unroll
            for (int it = 0; it < 16; ++it) {
                int jj = jb + it * 8;
                w1t[k][jj] = W1[jj * CH + k0 + k];
                wat[k][jj] = W2[jj * 2 * CH + k0 + k];
                wbt[k][jj] = W2[jj * 2 * CH + CH + k0 + k];
            }
        }
        __syncthreads();
#pragma unroll
        for (int kk = 0; kk < 32; ++kk) {
            float w1 = w1t[kk][j];
            float wa = wat[kk][j];
            float wb = wbt[kk][j];
#pragma unroll
            for (int r = 0; r < 4; ++r) {
                float rv = rs[rg * 4 + r][k0 + kk];
                float av = as_[rg * 4 + r][k0 + kk];
                acc1[r] = fmaf(rv, w1, acc1[r]);
                acc1[r] = fmaf(av, w1, acc1[r]);
                acc2[r] = fmaf(rv, wa, acc2[r]);
                acc2[r] = fmaf(av, wb, acc2[r]);
            }
        }
    }

    float bb1 = b1[j];
    float bb2 = b2[j];
#pragma unroll
    for (int r = 0; r < 4; ++r) {
        long long grow = row0 + rg * 4 + r;
        float e1 = acc1[r] + bb1;
        e1 = e1 >= 0.f ? e1 : LEAKY * e1;
        float e2 = acc2[r] + bb2;
        e2 = e2 >= 0.f ? e2 : LEAKY * e2;
        outp[grow * CH + j] = e1 + e2;
    }
}

// ---------------- copy weight to second output ------------------------------
__global__ __launch_bounds__(256) void copyw_kernel(const float* __restrict__ w,
                                                    float* __restrict__ out) {
    int i = blockIdx.x * 256 + threadIdx.x;
    if (i < 32 * CH) out[i] = w[i];
}

extern "C" void kernel_launch(void* const* d_in, const int* in_sizes, int n_in,
                              void* d_out, int out_size, void* d_ws, size_t ws_size,
                              hipStream_t stream) {
    const float* emb = (const float*)d_in[0];
    const int* eidx = (const int*)d_in[1];   // int inputs arrive as int32
    const int* etype = (const int*)d_in[2];
    const float* weight = (const float*)d_in[3];
    const float* W1w = (const float*)d_in[4];
    const float* W1b = (const float*)d_in[5];
    const float* W2w = (const float*)d_in[6];
    const float* W2b = (const float*)d_in[7];

    float* out = (float*)d_out;
    float* res_out = out;                     // [N_ENT][CH]
    float* wout = out + (size_t)N_ENT * CH;   // [32][CH]

    // workspace layout
    char* ws = (char*)d_ws;
    float* agg = (float*)ws;                          ws += (size_t)N_ENT * CH * 4;  // 25.6 MB
    int* packed = (int*)ws;                           ws += (size_t)N_EDG * 4;       // 2.4 MB
    int* offs = (int*)ws;                             ws += (size_t)(N_ENT + 1) * 4;
    int* cursors = (int*)ws;                          ws += (size_t)N_ENT * 4;
    int* counts = (int*)ws;                           ws += (size_t)N_ENT * 4;
    int* bsum = (int*)ws;                             ws += 64 * 4;

    const int* head = eidx;
    const int* tail = eidx + N_EDG;

    // ---- CSR build (hop-invariant, once per launch) ----
    hipMemsetAsync(counts, 0, N_ENT * sizeof(int), stream);
    count_kernel<<<(N_EDG + 255) / 256, 256, 0, stream>>>(head, counts);
    scan_block<<<NB_SCAN, 256, 0, stream>>>(counts, offs, bsum);
    scan_tops<<<1, 64, 0, stream>>>(bsum);
    add_base<<<NB_SCAN, 256, 0, stream>>>(offs, cursors, bsum);
    fill_kernel<<<(N_EDG + 255) / 256, 256, 0, stream>>>(head, tail, etype, cursors, packed);

    // ---- 2 hops ----
    const float* res_in = emb;
    for (int hop = 0; hop < 2; ++hop) {
        agg_kernel<<<N_ENT / 4, 256, 0, stream>>>(res_in, offs, packed, weight, agg);
        gemm_fused<<<N_ENT / 8, 256, 0, stream>>>(
            res_in, agg, W1w + hop * CH * CH, W1b + hop * CH,
            W2w + hop * 2 * CH * CH, W2b + hop * CH, res_out);
        res_in = res_out;
    }
    copyw_kernel<<<16, 256, 0, stream>>>(weight, wout);
}

// Round 4
// 303.330 us; speedup vs baseline: 8.5419x; 2.2301x over previous
//
#include <hip/hip_runtime.h>
#include <hip/hip_bf16.h>

#define N_ENT 50000
#define N_EDG 600000
#define CH 128
#define LEAKY 0.01f
#define NB_SCAN 49
#define NSTRIP 3125      // 50000 / 16
#define GEMM_BLOCKS 625  // 3125 / 625 = 5 strips per block, exact

typedef __attribute__((ext_vector_type(8))) short bf16x8;
typedef __attribute__((ext_vector_type(4))) float f32x4;

__device__ inline bf16x8 cvt8(const float* v) {
    bf16x8 r;
#pragma unroll
    for (int i = 0; i < 8; ++i)
        r[i] = __builtin_bit_cast(short, __float2bfloat16(v[i]));
    return r;
}

__device__ inline void split8(const float* v, bf16x8& hi, bf16x8& lo) {
#pragma unroll
    for (int i = 0; i < 8; ++i) {
        __hip_bfloat16 h = __float2bfloat16(v[i]);
        hi[i] = __builtin_bit_cast(short, h);
        lo[i] = __builtin_bit_cast(short, __float2bfloat16(v[i] - __bfloat162float(h)));
    }
}

// ---------------- CSR build step 1: in-degree counts ------------------------
__global__ __launch_bounds__(256) void count_kernel(const int* __restrict__ head,
                                                    int* __restrict__ counts) {
    int e = blockIdx.x * 256 + threadIdx.x;
    if (e < N_EDG) atomicAdd(&counts[head[e]], 1);
}

// ---------------- CSR step 2a: per-1024-chunk exclusive scan ----------------
__global__ __launch_bounds__(256) void scan_block(const int* __restrict__ counts,
                                                  int* __restrict__ offs,
                                                  int* __restrict__ bsum) {
    __shared__ int s[256];
    int t = threadIdx.x;
    int base = blockIdx.x * 1024 + t * 4;
    int v[4];
#pragma unroll
    for (int i = 0; i < 4; ++i) {
        int idx = base + i;
        v[i] = (idx < N_ENT) ? counts[idx] : 0;
    }
    int tot = v[0] + v[1] + v[2] + v[3];
    s[t] = tot;
    for (int off = 1; off < 256; off <<= 1) {
        __syncthreads();
        int x = (t >= off) ? s[t - off] : 0;
        __syncthreads();
        s[t] += x;
    }
    int run = s[t] - tot;
#pragma unroll
    for (int i = 0; i < 4; ++i) {
        if (base + i < N_ENT) offs[base + i] = run;
        run += v[i];
    }
    if (t == 255) bsum[blockIdx.x] = s[255];
}

// ---------------- CSR step 2b: scan the 49 chunk totals ----------------------
__global__ __launch_bounds__(64) void scan_tops(int* __restrict__ bsum) {
    int lane = threadIdx.x;
    int v = (lane < NB_SCAN) ? bsum[lane] : 0;
    int orig = v;
#pragma unroll
    for (int off = 1; off < 64; off <<= 1) {
        int x = __shfl_up(v, off);
        if (lane >= off) v += x;
    }
    if (lane < NB_SCAN) bsum[lane] = v - orig;
}

// ---------------- CSR step 2c: add chunk base, init cursors ------------------
__global__ __launch_bounds__(256) void add_base(int* __restrict__ offs,
                                                int* __restrict__ cursors,
                                                const int* __restrict__ bsum) {
    int t = threadIdx.x;
    int base = blockIdx.x * 1024 + t * 4;
    int b = bsum[blockIdx.x];
#pragma unroll
    for (int i = 0; i < 4; ++i) {
        int idx = base + i;
        if (idx < N_ENT) {
            int o = offs[idx] + b;
            offs[idx] = o;
            cursors[idx] = o;
        }
    }
    if (blockIdx.x == 0 && t == 0) offs[N_ENT] = N_EDG;
}

// ---------------- CSR step 3: fill packed edge payloads ----------------------
__global__ __launch_bounds__(256) void fill_kernel(const int* __restrict__ head,
                                                   const int* __restrict__ tail,
                                                   const int* __restrict__ etype,
                                                   int* __restrict__ cursors,
                                                   int* __restrict__ packed) {
    int e = blockIdx.x * 256 + threadIdx.x;
    if (e >= N_EDG) return;
    int h = head[e];
    int pos = atomicAdd(&cursors[h], 1);
    packed[pos] = tail[e] | (etype[e] << 20);
}

// ---------------- aggregate + mean + L2-normalize (fused) --------------------
__global__ __launch_bounds__(256) void agg_kernel(const float* __restrict__ res,
                                                  const int* __restrict__ offs,
                                                  const int* __restrict__ packed,
                                                  const float* __restrict__ weight,
                                                  float* __restrict__ agg) {
    __shared__ float ws[32 * CH];  // 16 KB relation weights
    int tid = threadIdx.x;
#pragma unroll
    for (int i = 0; i < 4; ++i)
        *(float4*)&ws[i * 1024 + tid * 4] = *(const float4*)&weight[i * 1024 + tid * 4];
    __syncthreads();

    int w = tid >> 6;
    int lane = tid & 63;
    int row = blockIdx.x * 4 + w;
    int beg = offs[row], end = offs[row + 1];

    float2 acc = {0.f, 0.f};
    for (int cb = beg; cb < end; cb += 64) {
        int n = min(64, end - cb);
        int myp = (cb + lane < end) ? packed[cb + lane] : 0;
        for (int i = 0; i < n; ++i) {
            int p = __shfl(myp, i);
            int t = p & 0xFFFFF;
            int r = p >> 20;
            float2 rv = *(const float2*)&res[(long long)t * CH + lane * 2];
            float2 wv = *(const float2*)&ws[r * CH + lane * 2];
            acc.x = fmaf(rv.x, wv.x, acc.x);
            acc.y = fmaf(rv.y, wv.y, acc.y);
        }
    }
    float d = fmaxf((float)(end - beg), 1.f);
    acc.x /= d;
    acc.y /= d;
    float ss = acc.x * acc.x + acc.y * acc.y;
#pragma unroll
    for (int off = 32; off >= 1; off >>= 1) ss += __shfl_xor(ss, off);
    float inv = 1.0f / fmaxf(sqrtf(ss), 1e-12f);
    float2 o = {acc.x * inv, acc.y * inv};
    *(float2*)&agg[(long long)row * CH + lane * 2] = o;
}

// ---------------- MFMA dual-GEMM + leaky + add -------------------------------
// out = leaky((res+agg)@W1^T + b1) + leaky(res@W2a^T + agg@W2b^T + b2)
// Expanded by linearity: acc1 = res@W1 + agg@W1 (hi+lo splits), so no f32 sum.
// Per block: 4 waves, wave w owns cols [32w, 32w+32); B-frags in registers.
// Strip = 16 rows; barrier between k-loop and stores (hop2 aliases resp/outp).
__global__ __launch_bounds__(256) void gemm_mfma(
    const float* resp, const float* __restrict__ aggp,
    const float* __restrict__ W1, const float* __restrict__ b1,
    const float* __restrict__ W2, const float* __restrict__ b2,
    float* outp) {
    const int tid = threadIdx.x;
    const int w = tid >> 6;
    const int lane = tid & 63;
    const int l16 = lane & 15;
    const int khi = (lane >> 4) * 8;

    // ---- load weight B-fragments into registers (once per block) ----
    // B[k][j] for mfma: j = lane&15 (col), k = khi + i (8 consecutive)
    bf16x8 bW1[2][4], bWa[2][4], bWb[2][4];
    float bb1[2], bb2[2];
#pragma unroll
    for (int nt = 0; nt < 2; ++nt) {
        int j = w * 32 + nt * 16 + l16;
        bb1[nt] = b1[j];
        bb2[nt] = b2[j];
#pragma unroll
        for (int kst = 0; kst < 4; ++kst) {
            int kk = kst * 32 + khi;
            float t[8];
            *(float4*)&t[0] = *(const float4*)&W1[j * CH + kk];
            *(float4*)&t[4] = *(const float4*)&W1[j * CH + kk + 4];
            bW1[nt][kst] = cvt8(t);
            *(float4*)&t[0] = *(const float4*)&W2[j * 2 * CH + kk];
            *(float4*)&t[4] = *(const float4*)&W2[j * 2 * CH + kk + 4];
            bWa[nt][kst] = cvt8(t);
            *(float4*)&t[0] = *(const float4*)&W2[j * 2 * CH + CH + kk];
            *(float4*)&t[4] = *(const float4*)&W2[j * 2 * CH + CH + kk + 4];
            bWb[nt][kst] = cvt8(t);
        }
    }

    for (int strip = blockIdx.x; strip < NSTRIP; strip += GEMM_BLOCKS) {
        int row0 = strip * 16;
        const float* rrow = resp + (long long)(row0 + l16) * CH + khi;
        const float* arow = aggp + (long long)(row0 + l16) * CH + khi;
        f32x4 acc1[2] = {{0.f, 0.f, 0.f, 0.f}, {0.f, 0.f, 0.f, 0.f}};
        f32x4 acc2[2] = {{0.f, 0.f, 0.f, 0.f}, {0.f, 0.f, 0.f, 0.f}};

#pragma unroll
        for (int kst = 0; kst < 4; ++kst) {
            float rv[8], av[8];
            *(float4*)&rv[0] = *(const float4*)&rrow[kst * 32];
            *(float4*)&rv[4] = *(const float4*)&rrow[kst * 32 + 4];
            *(float4*)&av[0] = *(const float4*)&arow[kst * 32];
            *(float4*)&av[4] = *(const float4*)&arow[kst * 32 + 4];
            bf16x8 rh, rl, ah, al;
            split8(rv, rh, rl);
            split8(av, ah, al);
#pragma unroll
            for (int nt = 0; nt < 2; ++nt) {
                acc1[nt] = __builtin_amdgcn_mfma_f32_16x16x32_bf16(rh, bW1[nt][kst], acc1[nt], 0, 0, 0);
                acc1[nt] = __builtin_amdgcn_mfma_f32_16x16x32_bf16(ah, bW1[nt][kst], acc1[nt], 0, 0, 0);
                acc1[nt] = __builtin_amdgcn_mfma_f32_16x16x32_bf16(rl, bW1[nt][kst], acc1[nt], 0, 0, 0);
                acc1[nt] = __builtin_amdgcn_mfma_f32_16x16x32_bf16(al, bW1[nt][kst], acc1[nt], 0, 0, 0);
                acc2[nt] = __builtin_amdgcn_mfma_f32_16x16x32_bf16(rh, bWa[nt][kst], acc2[nt], 0, 0, 0);
                acc2[nt] = __builtin_amdgcn_mfma_f32_16x16x32_bf16(rl, bWa[nt][kst], acc2[nt], 0, 0, 0);
                acc2[nt] = __builtin_amdgcn_mfma_f32_16x16x32_bf16(ah, bWb[nt][kst], acc2[nt], 0, 0, 0);
                acc2[nt] = __builtin_amdgcn_mfma_f32_16x16x32_bf16(al, bWb[nt][kst], acc2[nt], 0, 0, 0);
            }
        }

        // hop2 aliases resp/outp: all waves' loads must drain before any store
        __syncthreads();

#pragma unroll
        for (int nt = 0; nt < 2; ++nt) {
            int col = w * 32 + nt * 16 + l16;
#pragma unroll
            for (int r = 0; r < 4; ++r) {
                int row = row0 + (lane >> 4) * 4 + r;
                float e1 = acc1[nt][r] + bb1[nt];
                e1 = e1 >= 0.f ? e1 : LEAKY * e1;
                float e2 = acc2[nt][r] + bb2[nt];
                e2 = e2 >= 0.f ? e2 : LEAKY * e2;
                outp[(long long)row * CH + col] = e1 + e2;
            }
        }
    }
}

// ---------------- copy weight to second output ------------------------------
__global__ __launch_bounds__(256) void copyw_kernel(const float* __restrict__ w,
                                                    float* __restrict__ out) {
    int i = blockIdx.x * 256 + threadIdx.x;
    if (i < 32 * CH) out[i] = w[i];
}

extern "C" void kernel_launch(void* const* d_in, const int* in_sizes, int n_in,
                              void* d_out, int out_size, void* d_ws, size_t ws_size,
                              hipStream_t stream) {
    const float* emb = (const float*)d_in[0];
    const int* eidx = (const int*)d_in[1];   // int inputs arrive as int32
    const int* etype = (const int*)d_in[2];
    const float* weight = (const float*)d_in[3];
    const float* W1w = (const float*)d_in[4];
    const float* W1b = (const float*)d_in[5];
    const float* W2w = (const float*)d_in[6];
    const float* W2b = (const float*)d_in[7];

    float* out = (float*)d_out;
    float* res_out = out;                     // [N_ENT][CH]
    float* wout = out + (size_t)N_ENT * CH;   // [32][CH]

    // workspace layout
    char* ws = (char*)d_ws;
    float* agg = (float*)ws;                  ws += (size_t)N_ENT * CH * 4;  // 25.6 MB
    int* packed = (int*)ws;                   ws += (size_t)N_EDG * 4;       // 2.4 MB
    int* offs = (int*)ws;                     ws += (size_t)(N_ENT + 1) * 4;
    int* cursors = (int*)ws;                  ws += (size_t)N_ENT * 4;
    int* counts = (int*)ws;                   ws += (size_t)N_ENT * 4;
    int* bsum = (int*)ws;                     ws += 64 * 4;

    const int* head = eidx;
    const int* tail = eidx + N_EDG;

    // ---- CSR build (hop-invariant, once per launch) ----
    hipMemsetAsync(counts, 0, N_ENT * sizeof(int), stream);
    count_kernel<<<(N_EDG + 255) / 256, 256, 0, stream>>>(head, counts);
    scan_block<<<NB_SCAN, 256, 0, stream>>>(counts, offs, bsum);
    scan_tops<<<1, 64, 0, stream>>>(bsum);
    add_base<<<NB_SCAN, 256, 0, stream>>>(offs, cursors, bsum);
    fill_kernel<<<(N_EDG + 255) / 256, 256, 0, stream>>>(head, tail, etype, cursors, packed);

    // ---- 2 hops ----
    const float* res_in = emb;
    for (int hop = 0; hop < 2; ++hop) {
        agg_kernel<<<N_ENT / 4, 256, 0, stream>>>(res_in, offs, packed, weight, agg);
        gemm_mfma<<<GEMM_BLOCKS, 256, 0, stream>>>(
            res_in, agg, W1w + hop * CH * CH, W1b + hop * CH,
            W2w + hop * 2 * CH * CH, W2b + hop * CH, res_out);
        res_in = res_out;
    }
    copyw_kernel<<<16, 256, 0, stream>>>(weight, wout);
}

// Round 5
// 296.886 us; speedup vs baseline: 8.7273x; 1.0217x over previous
//
#include <hip/hip_runtime.h>
#include <hip/hip_bf16.h>

#define N_ENT 50000
#define N_EDG 600000
#define CH 128
#define LEAKY 0.01f
#define NB_SCAN 49
#define NSTRIP 3125       // 50000 / 16
#define GEMM_BLOCKS 1563  // ~2 strips per block

typedef __attribute__((ext_vector_type(8))) short bf16x8;
typedef __attribute__((ext_vector_type(4))) float f32x4;

__device__ inline bf16x8 cvt8(const float* v) {
    bf16x8 r;
#pragma unroll
    for (int i = 0; i < 8; ++i)
        r[i] = __builtin_bit_cast(short, __float2bfloat16(v[i]));
    return r;
}

__device__ inline void split8(const float* v, bf16x8& hi, bf16x8& lo) {
#pragma unroll
    for (int i = 0; i < 8; ++i) {
        __hip_bfloat16 h = __float2bfloat16(v[i]);
        hi[i] = __builtin_bit_cast(short, h);
        lo[i] = __builtin_bit_cast(short, __float2bfloat16(v[i] - __bfloat162float(h)));
    }
}

__device__ inline float bflo(unsigned u) {  // low ushort -> f32
    return __builtin_bit_cast(float, u << 16);
}
__device__ inline float bfhi(unsigned u) {  // high ushort -> f32
    return __builtin_bit_cast(float, u & 0xFFFF0000u);
}

// ---------------- CSR build step 1: in-degree counts ------------------------
__global__ __launch_bounds__(256) void count_kernel(const int* __restrict__ head,
                                                    int* __restrict__ counts) {
    int e = blockIdx.x * 256 + threadIdx.x;
    if (e < N_EDG) atomicAdd(&counts[head[e]], 1);
}

// ---------------- CSR step 2a: per-1024-chunk exclusive scan ----------------
__global__ __launch_bounds__(256) void scan_block(const int* __restrict__ counts,
                                                  int* __restrict__ offs,
                                                  int* __restrict__ bsum) {
    __shared__ int s[256];
    int t = threadIdx.x;
    int base = blockIdx.x * 1024 + t * 4;
    int v[4];
#pragma unroll
    for (int i = 0; i < 4; ++i) {
        int idx = base + i;
        v[i] = (idx < N_ENT) ? counts[idx] : 0;
    }
    int tot = v[0] + v[1] + v[2] + v[3];
    s[t] = tot;
    for (int off = 1; off < 256; off <<= 1) {
        __syncthreads();
        int x = (t >= off) ? s[t - off] : 0;
        __syncthreads();
        s[t] += x;
    }
    int run = s[t] - tot;
#pragma unroll
    for (int i = 0; i < 4; ++i) {
        if (base + i < N_ENT) offs[base + i] = run;
        run += v[i];
    }
    if (t == 255) bsum[blockIdx.x] = s[255];
}

// ---------------- CSR step 2b: scan the 49 chunk totals ----------------------
__global__ __launch_bounds__(64) void scan_tops(int* __restrict__ bsum) {
    int lane = threadIdx.x;
    int v = (lane < NB_SCAN) ? bsum[lane] : 0;
    int orig = v;
#pragma unroll
    for (int off = 1; off < 64; off <<= 1) {
        int x = __shfl_up(v, off);
        if (lane >= off) v += x;
    }
    if (lane < NB_SCAN) bsum[lane] = v - orig;
}

// ---------------- CSR step 2c: add chunk base, init cursors ------------------
__global__ __launch_bounds__(256) void add_base(int* __restrict__ offs,
                                                int* __restrict__ cursors,
                                                const int* __restrict__ bsum) {
    int t = threadIdx.x;
    int base = blockIdx.x * 1024 + t * 4;
    int b = bsum[blockIdx.x];
#pragma unroll
    for (int i = 0; i < 4; ++i) {
        int idx = base + i;
        if (idx < N_ENT) {
            int o = offs[idx] + b;
            offs[idx] = o;
            cursors[idx] = o;
        }
    }
    if (blockIdx.x == 0 && t == 0) offs[N_ENT] = N_EDG;
}

// ---------------- CSR step 3: fill packed edge payloads ----------------------
__global__ __launch_bounds__(256) void fill_kernel(const int* __restrict__ head,
                                                   const int* __restrict__ tail,
                                                   const int* __restrict__ etype,
                                                   int* __restrict__ cursors,
                                                   int* __restrict__ packed) {
    int e = blockIdx.x * 256 + threadIdx.x;
    if (e >= N_EDG) return;
    int h = head[e];
    int pos = atomicAdd(&cursors[h], 1);
    packed[pos] = tail[e] | (etype[e] << 20);
}

// ---------------- f32 -> bf16 row copy ---------------------------------------
__global__ __launch_bounds__(256) void cvt_bf_kernel(const float* __restrict__ src,
                                                     unsigned short* __restrict__ dst) {
    int i = blockIdx.x * 256 + threadIdx.x;  // one float4 per thread
    float4 v = *(const float4*)&src[(long long)i * 4];
    ushort4 o;
    o.x = __builtin_bit_cast(unsigned short, __float2bfloat16(v.x));
    o.y = __builtin_bit_cast(unsigned short, __float2bfloat16(v.y));
    o.z = __builtin_bit_cast(unsigned short, __float2bfloat16(v.z));
    o.w = __builtin_bit_cast(unsigned short, __float2bfloat16(v.w));
    *(ushort4*)&dst[(long long)i * 4] = o;
}

// ---------------- aggregate + mean + L2-normalize, bf16 gather ---------------
// one wave per head row; lane owns channels [2*lane, 2*lane+1]
// edge loop unrolled x4 with 4 accumulators (4 outstanding 256B gathers)
__global__ __launch_bounds__(256) void agg_kernel_bf(const unsigned short* __restrict__ resb,
                                                     const int* __restrict__ offs,
                                                     const int* __restrict__ packed,
                                                     const float* __restrict__ weight,
                                                     float* __restrict__ agg) {
    __shared__ float ws_[32 * CH];  // 16 KB relation weights, f32
    int tid = threadIdx.x;
#pragma unroll
    for (int i = 0; i < 4; ++i)
        *(float4*)&ws_[i * 1024 + tid * 4] = *(const float4*)&weight[i * 1024 + tid * 4];
    __syncthreads();

    int w = tid >> 6;
    int lane = tid & 63;
    int c2 = lane * 2;
    int row = blockIdx.x * 4 + w;
    int beg = offs[row], end = offs[row + 1];

    float2 a0 = {0.f, 0.f}, a1 = {0.f, 0.f}, a2 = {0.f, 0.f}, a3 = {0.f, 0.f};
    for (int cb = beg; cb < end; cb += 64) {
        int n = min(64, end - cb);
        int myp = (cb + lane < end) ? packed[cb + lane] : 0;
        int i = 0;
        for (; i + 4 <= n; i += 4) {
            int p0 = __shfl(myp, i);
            int p1 = __shfl(myp, i + 1);
            int p2 = __shfl(myp, i + 2);
            int p3 = __shfl(myp, i + 3);
            unsigned v0 = *(const unsigned*)&resb[(long long)(p0 & 0xFFFFF) * CH + c2];
            unsigned v1 = *(const unsigned*)&resb[(long long)(p1 & 0xFFFFF) * CH + c2];
            unsigned v2 = *(const unsigned*)&resb[(long long)(p2 & 0xFFFFF) * CH + c2];
            unsigned v3 = *(const unsigned*)&resb[(long long)(p3 & 0xFFFFF) * CH + c2];
            float2 w0 = *(const float2*)&ws_[(p0 >> 20) * CH + c2];
            float2 w1 = *(const float2*)&ws_[(p1 >> 20) * CH + c2];
            float2 w2 = *(const float2*)&ws_[(p2 >> 20) * CH + c2];
            float2 w3 = *(const float2*)&ws_[(p3 >> 20) * CH + c2];
            a0.x = fmaf(bflo(v0), w0.x, a0.x); a0.y = fmaf(bfhi(v0), w0.y, a0.y);
            a1.x = fmaf(bflo(v1), w1.x, a1.x); a1.y = fmaf(bfhi(v1), w1.y, a1.y);
            a2.x = fmaf(bflo(v2), w2.x, a2.x); a2.y = fmaf(bfhi(v2), w2.y, a2.y);
            a3.x = fmaf(bflo(v3), w3.x, a3.x); a3.y = fmaf(bfhi(v3), w3.y, a3.y);
        }
        for (; i < n; ++i) {
            int p = __shfl(myp, i);
            unsigned v = *(const unsigned*)&resb[(long long)(p & 0xFFFFF) * CH + c2];
            float2 wv = *(const float2*)&ws_[(p >> 20) * CH + c2];
            a0.x = fmaf(bflo(v), wv.x, a0.x);
            a0.y = fmaf(bfhi(v), wv.y, a0.y);
        }
    }
    float2 acc = {a0.x + a1.x + a2.x + a3.x, a0.y + a1.y + a2.y + a3.y};
    float d = fmaxf((float)(end - beg), 1.f);
    acc.x /= d;
    acc.y /= d;
    float ss = acc.x * acc.x + acc.y * acc.y;
#pragma unroll
    for (int off = 32; off >= 1; off >>= 1) ss += __shfl_xor(ss, off);
    float inv = 1.0f / fmaxf(sqrtf(ss), 1e-12f);
    float2 o = {acc.x * inv, acc.y * inv};
    *(float2*)&agg[(long long)row * CH + c2] = o;
}

// ---------------- f32-gather fallback (ws too small), same unroll ------------
__global__ __launch_bounds__(256) void agg_kernel_f32(const float* __restrict__ res,
                                                      const int* __restrict__ offs,
                                                      const int* __restrict__ packed,
                                                      const float* __restrict__ weight,
                                                      float* __restrict__ agg) {
    __shared__ float ws_[32 * CH];
    int tid = threadIdx.x;
#pragma unroll
    for (int i = 0; i < 4; ++i)
        *(float4*)&ws_[i * 1024 + tid * 4] = *(const float4*)&weight[i * 1024 + tid * 4];
    __syncthreads();

    int w = tid >> 6;
    int lane = tid & 63;
    int c2 = lane * 2;
    int row = blockIdx.x * 4 + w;
    int beg = offs[row], end = offs[row + 1];

    float2 a0 = {0.f, 0.f}, a1 = {0.f, 0.f}, a2 = {0.f, 0.f}, a3 = {0.f, 0.f};
    for (int cb = beg; cb < end; cb += 64) {
        int n = min(64, end - cb);
        int myp = (cb + lane < end) ? packed[cb + lane] : 0;
        int i = 0;
        for (; i + 4 <= n; i += 4) {
            int p0 = __shfl(myp, i), p1 = __shfl(myp, i + 1);
            int p2 = __shfl(myp, i + 2), p3 = __shfl(myp, i + 3);
            float2 r0 = *(const float2*)&res[(long long)(p0 & 0xFFFFF) * CH + c2];
            float2 r1 = *(const float2*)&res[(long long)(p1 & 0xFFFFF) * CH + c2];
            float2 r2 = *(const float2*)&res[(long long)(p2 & 0xFFFFF) * CH + c2];
            float2 r3 = *(const float2*)&res[(long long)(p3 & 0xFFFFF) * CH + c2];
            float2 w0 = *(const float2*)&ws_[(p0 >> 20) * CH + c2];
            float2 w1 = *(const float2*)&ws_[(p1 >> 20) * CH + c2];
            float2 w2 = *(const float2*)&ws_[(p2 >> 20) * CH + c2];
            float2 w3 = *(const float2*)&ws_[(p3 >> 20) * CH + c2];
            a0.x = fmaf(r0.x, w0.x, a0.x); a0.y = fmaf(r0.y, w0.y, a0.y);
            a1.x = fmaf(r1.x, w1.x, a1.x); a1.y = fmaf(r1.y, w1.y, a1.y);
            a2.x = fmaf(r2.x, w2.x, a2.x); a2.y = fmaf(r2.y, w2.y, a2.y);
            a3.x = fmaf(r3.x, w3.x, a3.x); a3.y = fmaf(r3.y, w3.y, a3.y);
        }
        for (; i < n; ++i) {
            int p = __shfl(myp, i);
            float2 rv = *(const float2*)&res[(long long)(p & 0xFFFFF) * CH + c2];
            float2 wv = *(const float2*)&ws_[(p >> 20) * CH + c2];
            a0.x = fmaf(rv.x, wv.x, a0.x);
            a0.y = fmaf(rv.y, wv.y, a0.y);
        }
    }
    float2 acc = {a0.x + a1.x + a2.x + a3.x, a0.y + a1.y + a2.y + a3.y};
    float d = fmaxf((float)(end - beg), 1.f);
    acc.x /= d;
    acc.y /= d;
    float ss = acc.x * acc.x + acc.y * acc.y;
#pragma unroll
    for (int off = 32; off >= 1; off >>= 1) ss += __shfl_xor(ss, off);
    float inv = 1.0f / fmaxf(sqrtf(ss), 1e-12f);
    float2 o = {acc.x * inv, acc.y * inv};
    *(float2*)&agg[(long long)row * CH + c2] = o;
}

// ---------------- MFMA dual-GEMM + leaky + add -------------------------------
// out = leaky((res+agg)@W1^T + b1) + leaky(res@W2a^T + agg@W2b^T + b2)
__global__ __launch_bounds__(256) void gemm_mfma(
    const float* resp, const float* __restrict__ aggp,
    const float* __restrict__ W1, const float* __restrict__ b1,
    const float* __restrict__ W2, const float* __restrict__ b2,
    float* outp, unsigned short* outb) {
    const int tid = threadIdx.x;
    const int w = tid >> 6;
    const int lane = tid & 63;
    const int l16 = lane & 15;
    const int khi = (lane >> 4) * 8;

    // weight B-fragments in registers (once per block)
    bf16x8 bW1[2][4], bWa[2][4], bWb[2][4];
    float bb1[2], bb2[2];
#pragma unroll
    for (int nt = 0; nt < 2; ++nt) {
        int j = w * 32 + nt * 16 + l16;
        bb1[nt] = b1[j];
        bb2[nt] = b2[j];
#pragma unroll
        for (int kst = 0; kst < 4; ++kst) {
            int kk = kst * 32 + khi;
            float t[8];
            *(float4*)&t[0] = *(const float4*)&W1[j * CH + kk];
            *(float4*)&t[4] = *(const float4*)&W1[j * CH + kk + 4];
            bW1[nt][kst] = cvt8(t);
            *(float4*)&t[0] = *(const float4*)&W2[j * 2 * CH + kk];
            *(float4*)&t[4] = *(const float4*)&W2[j * 2 * CH + kk + 4];
            bWa[nt][kst] = cvt8(t);
            *(float4*)&t[0] = *(const float4*)&W2[j * 2 * CH + CH + kk];
            *(float4*)&t[4] = *(const float4*)&W2[j * 2 * CH + CH + kk + 4];
            bWb[nt][kst] = cvt8(t);
        }
    }

    for (int strip = blockIdx.x; strip < NSTRIP; strip += GEMM_BLOCKS) {
        int row0 = strip * 16;
        const float* rrow = resp + (long long)(row0 + l16) * CH + khi;
        const float* arow = aggp + (long long)(row0 + l16) * CH + khi;
        f32x4 acc1[2] = {{0.f, 0.f, 0.f, 0.f}, {0.f, 0.f, 0.f, 0.f}};
        f32x4 acc2[2] = {{0.f, 0.f, 0.f, 0.f}, {0.f, 0.f, 0.f, 0.f}};

#pragma unroll
        for (int kst = 0; kst < 4; ++kst) {
            float rv[8], av[8];
            *(float4*)&rv[0] = *(const float4*)&rrow[kst * 32];
            *(float4*)&rv[4] = *(const float4*)&rrow[kst * 32 + 4];
            *(float4*)&av[0] = *(const float4*)&arow[kst * 32];
            *(float4*)&av[4] = *(const float4*)&arow[kst * 32 + 4];
            bf16x8 rh, rl, ah, al;
            split8(rv, rh, rl);
            split8(av, ah, al);
#pragma unroll
            for (int nt = 0; nt < 2; ++nt) {
                acc1[nt] = __builtin_amdgcn_mfma_f32_16x16x32_bf16(rh, bW1[nt][kst], acc1[nt], 0, 0, 0);
                acc1[nt] = __builtin_amdgcn_mfma_f32_16x16x32_bf16(ah, bW1[nt][kst], acc1[nt], 0, 0, 0);
                acc1[nt] = __builtin_amdgcn_mfma_f32_16x16x32_bf16(rl, bW1[nt][kst], acc1[nt], 0, 0, 0);
                acc1[nt] = __builtin_amdgcn_mfma_f32_16x16x32_bf16(al, bW1[nt][kst], acc1[nt], 0, 0, 0);
                acc2[nt] = __builtin_amdgcn_mfma_f32_16x16x32_bf16(rh, bWa[nt][kst], acc2[nt], 0, 0, 0);
                acc2[nt] = __builtin_amdgcn_mfma_f32_16x16x32_bf16(rl, bWa[nt][kst], acc2[nt], 0, 0, 0);
                acc2[nt] = __builtin_amdgcn_mfma_f32_16x16x32_bf16(ah, bWb[nt][kst], acc2[nt], 0, 0, 0);
                acc2[nt] = __builtin_amdgcn_mfma_f32_16x16x32_bf16(al, bWb[nt][kst], acc2[nt], 0, 0, 0);
            }
        }

        // hop2 aliases resp/outp: all waves' loads must drain before any store
        __syncthreads();

#pragma unroll
        for (int nt = 0; nt < 2; ++nt) {
            int col = w * 32 + nt * 16 + l16;
#pragma unroll
            for (int r = 0; r < 4; ++r) {
                int row = row0 + (lane >> 4) * 4 + r;
                float e1 = acc1[nt][r] + bb1[nt];
                e1 = e1 >= 0.f ? e1 : LEAKY * e1;
                float e2 = acc2[nt][r] + bb2[nt];
                e2 = e2 >= 0.f ? e2 : LEAKY * e2;
                float val = e1 + e2;
                outp[(long long)row * CH + col] = val;
                if (outb)
                    outb[(long long)row * CH + col] =
                        __builtin_bit_cast(unsigned short, __float2bfloat16(val));
            }
        }
    }
}

// ---------------- copy weight to second output ------------------------------
__global__ __launch_bounds__(256) void copyw_kernel(const float* __restrict__ w,
                                                    float* __restrict__ out) {
    int i = blockIdx.x * 256 + threadIdx.x;
    if (i < 32 * CH) out[i] = w[i];
}

extern "C" void kernel_launch(void* const* d_in, const int* in_sizes, int n_in,
                              void* d_out, int out_size, void* d_ws, size_t ws_size,
                              hipStream_t stream) {
    const float* emb = (const float*)d_in[0];
    const int* eidx = (const int*)d_in[1];   // int inputs arrive as int32
    const int* etype = (const int*)d_in[2];
    const float* weight = (const float*)d_in[3];
    const float* W1w = (const float*)d_in[4];
    const float* W1b = (const float*)d_in[5];
    const float* W2w = (const float*)d_in[6];
    const float* W2b = (const float*)d_in[7];

    float* out = (float*)d_out;
    float* res_out = out;                     // [N_ENT][CH]
    float* wout = out + (size_t)N_ENT * CH;   // [32][CH]

    // workspace layout
    char* ws = (char*)d_ws;
    float* agg = (float*)ws;                  ws += (size_t)N_ENT * CH * 4;  // 25.6 MB
    unsigned short* res_bf = (unsigned short*)ws;
    size_t bf_bytes = (size_t)N_ENT * CH * 2;                                // 12.8 MB
    bool use_bf = true;
    {
        size_t base = (size_t)N_ENT * CH * 4 + (size_t)N_EDG * 4 +
                      (size_t)(N_ENT + 1) * 4 + (size_t)N_ENT * 4 * 2 + 64 * 4;
        if (ws_size < base + bf_bytes) use_bf = false;
    }
    if (use_bf) ws += bf_bytes;
    int* packed = (int*)ws;                   ws += (size_t)N_EDG * 4;       // 2.4 MB
    int* offs = (int*)ws;                     ws += (size_t)(N_ENT + 1) * 4;
    int* cursors = (int*)ws;                  ws += (size_t)N_ENT * 4;
    int* counts = (int*)ws;                   ws += (size_t)N_ENT * 4;
    int* bsum = (int*)ws;                     ws += 64 * 4;

    const int* head = eidx;
    const int* tail = eidx + N_EDG;

    // ---- CSR build (hop-invariant, once per launch) ----
    hipMemsetAsync(counts, 0, N_ENT * sizeof(int), stream);
    count_kernel<<<(N_EDG + 255) / 256, 256, 0, stream>>>(head, counts);
    scan_block<<<NB_SCAN, 256, 0, stream>>>(counts, offs, bsum);
    scan_tops<<<1, 64, 0, stream>>>(bsum);
    add_base<<<NB_SCAN, 256, 0, stream>>>(offs, cursors, bsum);
    fill_kernel<<<(N_EDG + 255) / 256, 256, 0, stream>>>(head, tail, etype, cursors, packed);
    if (use_bf)
        cvt_bf_kernel<<<(N_ENT * CH / 4 + 255) / 256, 256, 0, stream>>>(emb, res_bf);

    // ---- 2 hops ----
    const float* res_in = emb;
    for (int hop = 0; hop < 2; ++hop) {
        if (use_bf)
            agg_kernel_bf<<<N_ENT / 4, 256, 0, stream>>>(res_bf, offs, packed, weight, agg);
        else
            agg_kernel_f32<<<N_ENT / 4, 256, 0, stream>>>(res_in, offs, packed, weight, agg);
        gemm_mfma<<<GEMM_BLOCKS, 256, 0, stream>>>(
            res_in, agg, W1w + hop * CH * CH, W1b + hop * CH,
            W2w + hop * 2 * CH * CH, W2b + hop * CH, res_out,
            (use_bf && hop == 0) ? res_bf : (unsigned short*)nullptr);
        res_in = res_out;
    }
    copyw_kernel<<<16, 256, 0, stream>>>(weight, wout);
}

// Round 6
// 246.200 us; speedup vs baseline: 10.5241x; 1.2059x over previous
//
#include <hip/hip_runtime.h>
#include <hip/hip_bf16.h>

#define N_ENT 50000
#define N_EDG 600000
#define CH 128
#define LEAKY 0.01f
#define NB_SCAN 49
#define NSTRIP 3125       // 50000 / 16
#define GEMM_BLOCKS 1563  // blocks 0..1561 do 2 strips, block 1562 does 1

typedef __attribute__((ext_vector_type(8))) short bf16x8;
typedef __attribute__((ext_vector_type(4))) float f32x4;

__device__ inline unsigned short f2bf(float x) {
    return __builtin_bit_cast(unsigned short, __float2bfloat16(x));
}
__device__ inline float bf2f(unsigned short u) {
    return __builtin_bit_cast(float, (unsigned)u << 16);
}
__device__ inline float bflo(unsigned u) { return __builtin_bit_cast(float, u << 16); }
__device__ inline float bfhi(unsigned u) { return __builtin_bit_cast(float, u & 0xFFFF0000u); }

// ---------------- CSR build step 1: in-degree counts ------------------------
__global__ __launch_bounds__(256) void count_kernel(const int* __restrict__ head,
                                                    int* __restrict__ counts) {
    int e = blockIdx.x * 256 + threadIdx.x;
    if (e < N_EDG) atomicAdd(&counts[head[e]], 1);
}

// ---------------- CSR step 2a: per-1024-chunk exclusive scan ----------------
__global__ __launch_bounds__(256) void scan_block(const int* __restrict__ counts,
                                                  int* __restrict__ offs,
                                                  int* __restrict__ bsum) {
    __shared__ int s[256];
    int t = threadIdx.x;
    int base = blockIdx.x * 1024 + t * 4;
    int v[4];
#pragma unroll
    for (int i = 0; i < 4; ++i) {
        int idx = base + i;
        v[i] = (idx < N_ENT) ? counts[idx] : 0;
    }
    int tot = v[0] + v[1] + v[2] + v[3];
    s[t] = tot;
    for (int off = 1; off < 256; off <<= 1) {
        __syncthreads();
        int x = (t >= off) ? s[t - off] : 0;
        __syncthreads();
        s[t] += x;
    }
    int run = s[t] - tot;
#pragma unroll
    for (int i = 0; i < 4; ++i) {
        if (base + i < N_ENT) offs[base + i] = run;
        run += v[i];
    }
    if (t == 255) bsum[blockIdx.x] = s[255];
}

// ---------------- CSR step 2b: scan the 49 chunk totals ----------------------
__global__ __launch_bounds__(64) void scan_tops(int* __restrict__ bsum) {
    int lane = threadIdx.x;
    int v = (lane < NB_SCAN) ? bsum[lane] : 0;
    int orig = v;
#pragma unroll
    for (int off = 1; off < 64; off <<= 1) {
        int x = __shfl_up(v, off);
        if (lane >= off) v += x;
    }
    if (lane < NB_SCAN) bsum[lane] = v - orig;
}

// ---------------- CSR step 2c: add chunk base, init cursors ------------------
__global__ __launch_bounds__(256) void add_base(int* __restrict__ offs,
                                                int* __restrict__ cursors,
                                                const int* __restrict__ bsum) {
    int t = threadIdx.x;
    int base = blockIdx.x * 1024 + t * 4;
    int b = bsum[blockIdx.x];
#pragma unroll
    for (int i = 0; i < 4; ++i) {
        int idx = base + i;
        if (idx < N_ENT) {
            int o = offs[idx] + b;
            offs[idx] = o;
            cursors[idx] = o;
        }
    }
    if (blockIdx.x == 0 && t == 0) offs[N_ENT] = N_EDG;
}

// ---------------- CSR step 3: fill packed edge payloads ----------------------
__global__ __launch_bounds__(256) void fill_kernel(const int* __restrict__ head,
                                                   const int* __restrict__ tail,
                                                   const int* __restrict__ etype,
                                                   int* __restrict__ cursors,
                                                   int* __restrict__ packed) {
    int e = blockIdx.x * 256 + threadIdx.x;
    if (e >= N_EDG) return;
    int h = head[e];
    int pos = atomicAdd(&cursors[h], 1);
    packed[pos] = tail[e] | (etype[e] << 20);
}

// ---------------- f32 -> (hi, lo) bf16 planes --------------------------------
__global__ __launch_bounds__(256) void cvt_split_kernel(const float* __restrict__ src,
                                                        unsigned short* __restrict__ hi,
                                                        unsigned short* __restrict__ lo) {
    long long i = ((long long)blockIdx.x * 256 + threadIdx.x) * 4;
    float4 v = *(const float4*)&src[i];
    ushort4 h, l;
    h.x = f2bf(v.x); l.x = f2bf(v.x - bf2f(h.x));
    h.y = f2bf(v.y); l.y = f2bf(v.y - bf2f(h.y));
    h.z = f2bf(v.z); l.z = f2bf(v.z - bf2f(h.z));
    h.w = f2bf(v.w); l.w = f2bf(v.w - bf2f(h.w));
    *(ushort4*)&hi[i] = h;
    *(ushort4*)&lo[i] = l;
}

// ---------------- f32 -> bf16 weights (both hops) ----------------------------
// W1w: 2*128*128 floats = 8192 float4; W2w: 2*128*256 = 16384 float4
__global__ __launch_bounds__(256) void cvt_w_kernel(const float* __restrict__ W1,
                                                    const float* __restrict__ W2,
                                                    unsigned short* __restrict__ w1bf,
                                                    unsigned short* __restrict__ w2bf) {
    int i = blockIdx.x * 256 + threadIdx.x;  // float4 index, 24576 total
    const float* src;
    unsigned short* dst;
    long long k;
    if (i < 8192) { src = W1; dst = w1bf; k = (long long)i * 4; }
    else          { src = W2; dst = w2bf; k = (long long)(i - 8192) * 4; }
    float4 v = *(const float4*)&src[k];
    ushort4 o;
    o.x = f2bf(v.x); o.y = f2bf(v.y); o.z = f2bf(v.z); o.w = f2bf(v.w);
    *(ushort4*)&dst[k] = o;
}

// ---------------- aggregate + mean + L2-normalize (bf16 in/out) --------------
// one wave per head row; lane owns channels [2*lane, 2*lane+1]; x4 unroll
__global__ __launch_bounds__(256) void agg_kernel(const unsigned short* __restrict__ xh,
                                                  const int* __restrict__ offs,
                                                  const int* __restrict__ packed,
                                                  const float* __restrict__ weight,
                                                  unsigned short* __restrict__ aggb) {
    __shared__ float ws_[32 * CH];  // 16 KB relation weights, f32
    int tid = threadIdx.x;
#pragma unroll
    for (int i = 0; i < 4; ++i)
        *(float4*)&ws_[i * 1024 + tid * 4] = *(const float4*)&weight[i * 1024 + tid * 4];
    __syncthreads();

    int w = tid >> 6;
    int lane = tid & 63;
    int c2 = lane * 2;
    int row = blockIdx.x * 4 + w;
    int beg = offs[row], end = offs[row + 1];

    float2 a0 = {0.f, 0.f}, a1 = {0.f, 0.f}, a2 = {0.f, 0.f}, a3 = {0.f, 0.f};
    for (int cb = beg; cb < end; cb += 64) {
        int n = min(64, end - cb);
        int myp = (cb + lane < end) ? packed[cb + lane] : 0;
        int i = 0;
        for (; i + 4 <= n; i += 4) {
            int p0 = __shfl(myp, i);
            int p1 = __shfl(myp, i + 1);
            int p2 = __shfl(myp, i + 2);
            int p3 = __shfl(myp, i + 3);
            unsigned v0 = *(const unsigned*)&xh[(long long)(p0 & 0xFFFFF) * CH + c2];
            unsigned v1 = *(const unsigned*)&xh[(long long)(p1 & 0xFFFFF) * CH + c2];
            unsigned v2 = *(const unsigned*)&xh[(long long)(p2 & 0xFFFFF) * CH + c2];
            unsigned v3 = *(const unsigned*)&xh[(long long)(p3 & 0xFFFFF) * CH + c2];
            float2 w0 = *(const float2*)&ws_[(p0 >> 20) * CH + c2];
            float2 w1 = *(const float2*)&ws_[(p1 >> 20) * CH + c2];
            float2 w2 = *(const float2*)&ws_[(p2 >> 20) * CH + c2];
            float2 w3 = *(const float2*)&ws_[(p3 >> 20) * CH + c2];
            a0.x = fmaf(bflo(v0), w0.x, a0.x); a0.y = fmaf(bfhi(v0), w0.y, a0.y);
            a1.x = fmaf(bflo(v1), w1.x, a1.x); a1.y = fmaf(bfhi(v1), w1.y, a1.y);
            a2.x = fmaf(bflo(v2), w2.x, a2.x); a2.y = fmaf(bfhi(v2), w2.y, a2.y);
            a3.x = fmaf(bflo(v3), w3.x, a3.x); a3.y = fmaf(bfhi(v3), w3.y, a3.y);
        }
        for (; i < n; ++i) {
            int p = __shfl(myp, i);
            unsigned v = *(const unsigned*)&xh[(long long)(p & 0xFFFFF) * CH + c2];
            float2 wv = *(const float2*)&ws_[(p >> 20) * CH + c2];
            a0.x = fmaf(bflo(v), wv.x, a0.x);
            a0.y = fmaf(bfhi(v), wv.y, a0.y);
        }
    }
    float2 acc = {a0.x + a1.x + a2.x + a3.x, a0.y + a1.y + a2.y + a3.y};
    float d = fmaxf((float)(end - beg), 1.f);
    acc.x /= d;
    acc.y /= d;
    float ss = acc.x * acc.x + acc.y * acc.y;
#pragma unroll
    for (int off = 32; off >= 1; off >>= 1) ss += __shfl_xor(ss, off);
    float inv = 1.0f / fmaxf(sqrtf(ss), 1e-12f);
    ushort2 o;
    o.x = f2bf(acc.x * inv);
    o.y = f2bf(acc.y * inv);
    *(ushort2*)&aggb[(long long)row * CH + c2] = o;
}

// ---------------- MFMA dual-GEMM + leaky + add -------------------------------
// acc1 = (x_hi + x_lo + agg) @ W1^T ;  acc2 = (x_hi + x_lo) @ W2a^T + agg @ W2b^T
// All operands pre-converted bf16; zero conversion VALU in the loop.
// hop1 (outf==null): writes x_hi/x_lo in place (barrier covers intra-block race)
// hop2: writes f32 d_out, no barrier needed.
__global__ __launch_bounds__(256) void gemm_mfma(
    unsigned short* xh, unsigned short* xl,
    const unsigned short* __restrict__ aggb,
    const unsigned short* __restrict__ w1bf, const unsigned short* __restrict__ w2bf,
    const float* __restrict__ b1, const float* __restrict__ b2,
    float* outf) {
    const int tid = threadIdx.x;
    const int w = tid >> 6;
    const int lane = tid & 63;
    const int l16 = lane & 15;
    const int khi = (lane >> 4) * 8;

    // weight B-fragments: direct bf16 16B loads, no conversion
    bf16x8 bW1[2][4], bWa[2][4], bWb[2][4];
    float bb1[2], bb2[2];
#pragma unroll
    for (int nt = 0; nt < 2; ++nt) {
        int j = w * 32 + nt * 16 + l16;
        bb1[nt] = b1[j];
        bb2[nt] = b2[j];
#pragma unroll
        for (int kst = 0; kst < 4; ++kst) {
            int kk = kst * 32 + khi;
            bW1[nt][kst] = *(const bf16x8*)&w1bf[j * CH + kk];
            bWa[nt][kst] = *(const bf16x8*)&w2bf[j * 2 * CH + kk];
            bWb[nt][kst] = *(const bf16x8*)&w2bf[j * 2 * CH + CH + kk];
        }
    }

    for (int strip = blockIdx.x; strip < NSTRIP; strip += GEMM_BLOCKS) {
        int row0 = strip * 16;
        long long abase = (long long)(row0 + l16) * CH + khi;
        f32x4 acc1[2] = {{0.f, 0.f, 0.f, 0.f}, {0.f, 0.f, 0.f, 0.f}};
        f32x4 acc2[2] = {{0.f, 0.f, 0.f, 0.f}, {0.f, 0.f, 0.f, 0.f}};

#pragma unroll
        for (int kst = 0; kst < 4; ++kst) {
            bf16x8 rh = *(const bf16x8*)&xh[abase + kst * 32];
            bf16x8 rl = *(const bf16x8*)&xl[abase + kst * 32];
            bf16x8 av = *(const bf16x8*)&aggb[abase + kst * 32];
#pragma unroll
            for (int nt = 0; nt < 2; ++nt) {
                acc1[nt] = __builtin_amdgcn_mfma_f32_16x16x32_bf16(rh, bW1[nt][kst], acc1[nt], 0, 0, 0);
                acc1[nt] = __builtin_amdgcn_mfma_f32_16x16x32_bf16(rl, bW1[nt][kst], acc1[nt], 0, 0, 0);
                acc1[nt] = __builtin_amdgcn_mfma_f32_16x16x32_bf16(av, bW1[nt][kst], acc1[nt], 0, 0, 0);
                acc2[nt] = __builtin_amdgcn_mfma_f32_16x16x32_bf16(rh, bWa[nt][kst], acc2[nt], 0, 0, 0);
                acc2[nt] = __builtin_amdgcn_mfma_f32_16x16x32_bf16(rl, bWa[nt][kst], acc2[nt], 0, 0, 0);
                acc2[nt] = __builtin_amdgcn_mfma_f32_16x16x32_bf16(av, bWb[nt][kst], acc2[nt], 0, 0, 0);
            }
        }

        // hop1 writes x in place: other waves read all cols of these rows
        if (outf == nullptr) __syncthreads();

#pragma unroll
        for (int nt = 0; nt < 2; ++nt) {
            int col = w * 32 + nt * 16 + l16;
#pragma unroll
            for (int r = 0; r < 4; ++r) {
                long long row = row0 + (lane >> 4) * 4 + r;
                float e1 = acc1[nt][r] + bb1[nt];
                e1 = e1 >= 0.f ? e1 : LEAKY * e1;
                float e2 = acc2[nt][r] + bb2[nt];
                e2 = e2 >= 0.f ? e2 : LEAKY * e2;
                float val = e1 + e2;
                if (outf) {
                    outf[row * CH + col] = val;
                } else {
                    unsigned short h = f2bf(val);
                    xh[row * CH + col] = h;
                    xl[row * CH + col] = f2bf(val - bf2f(h));
                }
            }
        }
    }
}

// ---------------- copy weight to second output ------------------------------
__global__ __launch_bounds__(256) void copyw_kernel(const float* __restrict__ w,
                                                    float* __restrict__ out) {
    int i = blockIdx.x * 256 + threadIdx.x;
    if (i < 32 * CH) out[i] = w[i];
}

extern "C" void kernel_launch(void* const* d_in, const int* in_sizes, int n_in,
                              void* d_out, int out_size, void* d_ws, size_t ws_size,
                              hipStream_t stream) {
    const float* emb = (const float*)d_in[0];
    const int* eidx = (const int*)d_in[1];   // int inputs arrive as int32
    const int* etype = (const int*)d_in[2];
    const float* weight = (const float*)d_in[3];
    const float* W1w = (const float*)d_in[4];
    const float* W1b = (const float*)d_in[5];
    const float* W2w = (const float*)d_in[6];
    const float* W2b = (const float*)d_in[7];

    float* out = (float*)d_out;
    float* wout = out + (size_t)N_ENT * CH;   // [32][CH]

    // workspace layout (~41.7 MB, fits proven >=43.5 MB)
    char* ws = (char*)d_ws;
    unsigned short* x_hi = (unsigned short*)ws;  ws += (size_t)N_ENT * CH * 2;  // 12.8 MB
    unsigned short* x_lo = (unsigned short*)ws;  ws += (size_t)N_ENT * CH * 2;  // 12.8 MB
    unsigned short* aggb = (unsigned short*)ws;  ws += (size_t)N_ENT * CH * 2;  // 12.8 MB
    unsigned short* w1bf = (unsigned short*)ws;  ws += 2 * CH * CH * 2;         // 64 KB
    unsigned short* w2bf = (unsigned short*)ws;  ws += 2 * CH * 2 * CH * 2;     // 128 KB
    int* packed = (int*)ws;                      ws += (size_t)N_EDG * 4;       // 2.4 MB
    int* offs = (int*)ws;                        ws += (size_t)(N_ENT + 1) * 4;
    int* cursors = (int*)ws;                     ws += (size_t)N_ENT * 4;
    int* counts = (int*)ws;                      ws += (size_t)N_ENT * 4;
    int* bsum = (int*)ws;                        ws += 64 * 4;

    const int* head = eidx;
    const int* tail = eidx + N_EDG;

    // ---- one-time prep: CSR + bf16 operand planes ----
    hipMemsetAsync(counts, 0, N_ENT * sizeof(int), stream);
    count_kernel<<<(N_EDG + 255) / 256, 256, 0, stream>>>(head, counts);
    scan_block<<<NB_SCAN, 256, 0, stream>>>(counts, offs, bsum);
    scan_tops<<<1, 64, 0, stream>>>(bsum);
    add_base<<<NB_SCAN, 256, 0, stream>>>(offs, cursors, bsum);
    fill_kernel<<<(N_EDG + 255) / 256, 256, 0, stream>>>(head, tail, etype, cursors, packed);
    cvt_split_kernel<<<N_ENT * CH / 4 / 256, 256, 0, stream>>>(emb, x_hi, x_lo);
    cvt_w_kernel<<<96, 256, 0, stream>>>(W1w, W2w, w1bf, w2bf);

    // ---- 2 hops ----
    for (int hop = 0; hop < 2; ++hop) {
        agg_kernel<<<N_ENT / 4, 256, 0, stream>>>(x_hi, offs, packed, weight, aggb);
        gemm_mfma<<<GEMM_BLOCKS, 256, 0, stream>>>(
            x_hi, x_lo, aggb, w1bf + hop * CH * CH, w2bf + hop * CH * 2 * CH,
            W1b + hop * CH, W2b + hop * CH,
            hop == 1 ? out : (float*)nullptr);
    }
    copyw_kernel<<<16, 256, 0, stream>>>(weight, wout);
}

// Round 7
// 238.547 us; speedup vs baseline: 10.8617x; 1.0321x over previous
//
#include <hip/hip_runtime.h>
#include <hip/hip_bf16.h>

#define N_ENT 50000
#define N_EDG 600000
#define CH 128
#define LEAKY 0.01f
#define NB_SCAN 49
#define NSTRIP 3125       // 50000 / 16
#define GEMM_BLOCKS 1042  // 3 strips per block (last block: 2)

typedef __attribute__((ext_vector_type(8))) short bf16x8;
typedef __attribute__((ext_vector_type(4))) float f32x4;

__device__ inline unsigned short f2bf(float x) {
    return __builtin_bit_cast(unsigned short, __float2bfloat16(x));
}
__device__ inline float bf2f(unsigned short u) {
    return __builtin_bit_cast(float, (unsigned)u << 16);
}
__device__ inline float bflo(unsigned u) { return __builtin_bit_cast(float, u << 16); }
__device__ inline float bfhi(unsigned u) { return __builtin_bit_cast(float, u & 0xFFFF0000u); }

// ---------------- CSR build step 1: in-degree counts ------------------------
__global__ __launch_bounds__(256) void count_kernel(const int* __restrict__ head,
                                                    int* __restrict__ counts) {
    int e = blockIdx.x * 256 + threadIdx.x;
    if (e < N_EDG) atomicAdd(&counts[head[e]], 1);
}

// ---------------- CSR step 2a: per-1024-chunk exclusive scan ----------------
__global__ __launch_bounds__(256) void scan_block(const int* __restrict__ counts,
                                                  int* __restrict__ offs,
                                                  int* __restrict__ bsum) {
    __shared__ int s[256];
    int t = threadIdx.x;
    int base = blockIdx.x * 1024 + t * 4;
    int v[4];
#pragma unroll
    for (int i = 0; i < 4; ++i) {
        int idx = base + i;
        v[i] = (idx < N_ENT) ? counts[idx] : 0;
    }
    int tot = v[0] + v[1] + v[2] + v[3];
    s[t] = tot;
    for (int off = 1; off < 256; off <<= 1) {
        __syncthreads();
        int x = (t >= off) ? s[t - off] : 0;
        __syncthreads();
        s[t] += x;
    }
    int run = s[t] - tot;
#pragma unroll
    for (int i = 0; i < 4; ++i) {
        if (base + i < N_ENT) offs[base + i] = run;
        run += v[i];
    }
    if (t == 255) bsum[blockIdx.x] = s[255];
}

// ---------------- CSR step 2b: scan the 49 chunk totals ----------------------
__global__ __launch_bounds__(64) void scan_tops(int* __restrict__ bsum) {
    int lane = threadIdx.x;
    int v = (lane < NB_SCAN) ? bsum[lane] : 0;
    int orig = v;
#pragma unroll
    for (int off = 1; off < 64; off <<= 1) {
        int x = __shfl_up(v, off);
        if (lane >= off) v += x;
    }
    if (lane < NB_SCAN) bsum[lane] = v - orig;
}

// ---------------- CSR step 2c: add chunk base, init cursors ------------------
__global__ __launch_bounds__(256) void add_base(int* __restrict__ offs,
                                                int* __restrict__ cursors,
                                                const int* __restrict__ bsum) {
    int t = threadIdx.x;
    int base = blockIdx.x * 1024 + t * 4;
    int b = bsum[blockIdx.x];
#pragma unroll
    for (int i = 0; i < 4; ++i) {
        int idx = base + i;
        if (idx < N_ENT) {
            int o = offs[idx] + b;
            offs[idx] = o;
            cursors[idx] = o;
        }
    }
    if (blockIdx.x == 0 && t == 0) offs[N_ENT] = N_EDG;
}

// ---------------- CSR step 3: fill packed edge payloads ----------------------
__global__ __launch_bounds__(256) void fill_kernel(const int* __restrict__ head,
                                                   const int* __restrict__ tail,
                                                   const int* __restrict__ etype,
                                                   int* __restrict__ cursors,
                                                   int* __restrict__ packed) {
    int e = blockIdx.x * 256 + threadIdx.x;
    if (e >= N_EDG) return;
    int h = head[e];
    int pos = atomicAdd(&cursors[h], 1);
    packed[pos] = tail[e] | (etype[e] << 20);
}

// ---------------- f32 -> (hi, lo) bf16 planes --------------------------------
__global__ __launch_bounds__(256) void cvt_split_kernel(const float* __restrict__ src,
                                                        unsigned short* __restrict__ hi,
                                                        unsigned short* __restrict__ lo) {
    long long i = ((long long)blockIdx.x * 256 + threadIdx.x) * 4;
    float4 v = *(const float4*)&src[i];
    ushort4 h, l;
    h.x = f2bf(v.x); l.x = f2bf(v.x - bf2f(h.x));
    h.y = f2bf(v.y); l.y = f2bf(v.y - bf2f(h.y));
    h.z = f2bf(v.z); l.z = f2bf(v.z - bf2f(h.z));
    h.w = f2bf(v.w); l.w = f2bf(v.w - bf2f(h.w));
    *(ushort4*)&hi[i] = h;
    *(ushort4*)&lo[i] = l;
}

// ---------------- f32 -> bf16 weights (both hops) ----------------------------
__global__ __launch_bounds__(256) void cvt_w_kernel(const float* __restrict__ W1,
                                                    const float* __restrict__ W2,
                                                    unsigned short* __restrict__ w1bf,
                                                    unsigned short* __restrict__ w2bf) {
    int i = blockIdx.x * 256 + threadIdx.x;  // float4 index, 24576 total
    const float* src;
    unsigned short* dst;
    long long k;
    if (i < 8192) { src = W1; dst = w1bf; k = (long long)i * 4; }
    else          { src = W2; dst = w2bf; k = (long long)(i - 8192) * 4; }
    float4 v = *(const float4*)&src[k];
    ushort4 o;
    o.x = f2bf(v.x); o.y = f2bf(v.y); o.z = f2bf(v.z); o.w = f2bf(v.w);
    *(ushort4*)&dst[k] = o;
}

// ---------------- aggregate + mean + L2-normalize (bf16 in/out) --------------
__global__ __launch_bounds__(256) void agg_kernel(const unsigned short* __restrict__ xh,
                                                  const int* __restrict__ offs,
                                                  const int* __restrict__ packed,
                                                  const float* __restrict__ weight,
                                                  unsigned short* __restrict__ aggb) {
    __shared__ float ws_[32 * CH];  // 16 KB relation weights, f32
    int tid = threadIdx.x;
#pragma unroll
    for (int i = 0; i < 4; ++i)
        *(float4*)&ws_[i * 1024 + tid * 4] = *(const float4*)&weight[i * 1024 + tid * 4];
    __syncthreads();

    int w = tid >> 6;
    int lane = tid & 63;
    int c2 = lane * 2;
    int row = blockIdx.x * 4 + w;
    int beg = offs[row], end = offs[row + 1];

    float2 a0 = {0.f, 0.f}, a1 = {0.f, 0.f}, a2 = {0.f, 0.f}, a3 = {0.f, 0.f};
    for (int cb = beg; cb < end; cb += 64) {
        int n = min(64, end - cb);
        int myp = (cb + lane < end) ? packed[cb + lane] : 0;
        int i = 0;
        for (; i + 4 <= n; i += 4) {
            int p0 = __shfl(myp, i);
            int p1 = __shfl(myp, i + 1);
            int p2 = __shfl(myp, i + 2);
            int p3 = __shfl(myp, i + 3);
            unsigned v0 = *(const unsigned*)&xh[(long long)(p0 & 0xFFFFF) * CH + c2];
            unsigned v1 = *(const unsigned*)&xh[(long long)(p1 & 0xFFFFF) * CH + c2];
            unsigned v2 = *(const unsigned*)&xh[(long long)(p2 & 0xFFFFF) * CH + c2];
            unsigned v3 = *(const unsigned*)&xh[(long long)(p3 & 0xFFFFF) * CH + c2];
            float2 w0 = *(const float2*)&ws_[(p0 >> 20) * CH + c2];
            float2 w1 = *(const float2*)&ws_[(p1 >> 20) * CH + c2];
            float2 w2 = *(const float2*)&ws_[(p2 >> 20) * CH + c2];
            float2 w3 = *(const float2*)&ws_[(p3 >> 20) * CH + c2];
            a0.x = fmaf(bflo(v0), w0.x, a0.x); a0.y = fmaf(bfhi(v0), w0.y, a0.y);
            a1.x = fmaf(bflo(v1), w1.x, a1.x); a1.y = fmaf(bfhi(v1), w1.y, a1.y);
            a2.x = fmaf(bflo(v2), w2.x, a2.x); a2.y = fmaf(bfhi(v2), w2.y, a2.y);
            a3.x = fmaf(bflo(v3), w3.x, a3.x); a3.y = fmaf(bfhi(v3), w3.y, a3.y);
        }
        for (; i < n; ++i) {
            int p = __shfl(myp, i);
            unsigned v = *(const unsigned*)&xh[(long long)(p & 0xFFFFF) * CH + c2];
            float2 wv = *(const float2*)&ws_[(p >> 20) * CH + c2];
            a0.x = fmaf(bflo(v), wv.x, a0.x);
            a0.y = fmaf(bfhi(v), wv.y, a0.y);
        }
    }
    float2 acc = {a0.x + a1.x + a2.x + a3.x, a0.y + a1.y + a2.y + a3.y};
    float d = fmaxf((float)(end - beg), 1.f);
    acc.x /= d;
    acc.y /= d;
    float ss = acc.x * acc.x + acc.y * acc.y;
#pragma unroll
    for (int off = 32; off >= 1; off >>= 1) ss += __shfl_xor(ss, off);
    float inv = 1.0f / fmaxf(sqrtf(ss), 1e-12f);
    ushort2 o;
    o.x = f2bf(acc.x * inv);
    o.y = f2bf(acc.y * inv);
    *(ushort2*)&aggb[(long long)row * CH + c2] = o;
}

// ---------------- MFMA dual-GEMM + leaky + add -------------------------------
// Weights register-resident (launch_bounds grants VGPR headroom); A-operands
// double-buffered with one-strip-ahead prefetch (macro ping-pong, static idx).
// hop1 (outf==null): writes x_hi/x_lo in place. Prefetch of strip i+1 (rows
// owned by this block only) is drained by the pre-store barrier -> race-free.
#define LOADA(RH, RL, AV, STRIP)                                      \
    {                                                                 \
        long long ab_ = (long long)((STRIP) * 16 + l16) * CH + khi;   \
        _Pragma("unroll") for (int k_ = 0; k_ < 4; ++k_) {            \
            RH[k_] = *(const bf16x8*)&xh[ab_ + k_ * 32];              \
            RL[k_] = *(const bf16x8*)&xl[ab_ + k_ * 32];              \
            AV[k_] = *(const bf16x8*)&aggb[ab_ + k_ * 32];            \
        }                                                             \
    }

#define COMPUTE(RH, RL, AV, STRIP)                                                              \
    {                                                                                           \
        f32x4 acc1[2] = {{0.f, 0.f, 0.f, 0.f}, {0.f, 0.f, 0.f, 0.f}};                           \
        f32x4 acc2[2] = {{0.f, 0.f, 0.f, 0.f}, {0.f, 0.f, 0.f, 0.f}};                           \
        _Pragma("unroll") for (int kst = 0; kst < 4; ++kst) {                                   \
            _Pragma("unroll") for (int nt = 0; nt < 2; ++nt) {                                  \
                acc1[nt] = __builtin_amdgcn_mfma_f32_16x16x32_bf16(RH[kst], bW1[nt][kst],       \
                                                                   acc1[nt], 0, 0, 0);          \
                acc1[nt] = __builtin_amdgcn_mfma_f32_16x16x32_bf16(RL[kst], bW1[nt][kst],       \
                                                                   acc1[nt], 0, 0, 0);          \
                acc1[nt] = __builtin_amdgcn_mfma_f32_16x16x32_bf16(AV[kst], bW1[nt][kst],       \
                                                                   acc1[nt], 0, 0, 0);          \
                acc2[nt] = __builtin_amdgcn_mfma_f32_16x16x32_bf16(RH[kst], bWa[nt][kst],       \
                                                                   acc2[nt], 0, 0, 0);          \
                acc2[nt] = __builtin_amdgcn_mfma_f32_16x16x32_bf16(RL[kst], bWa[nt][kst],       \
                                                                   acc2[nt], 0, 0, 0);          \
                acc2[nt] = __builtin_amdgcn_mfma_f32_16x16x32_bf16(AV[kst], bWb[nt][kst],       \
                                                                   acc2[nt], 0, 0, 0);          \
            }                                                                                   \
        }                                                                                       \
        if (outf == nullptr) __syncthreads();                                                   \
        _Pragma("unroll") for (int nt = 0; nt < 2; ++nt) {                                      \
            int col = w * 32 + nt * 16 + l16;                                                   \
            _Pragma("unroll") for (int r = 0; r < 4; ++r) {                                     \
                long long row = (long long)(STRIP)*16 + (lane >> 4) * 4 + r;                    \
                float e1 = acc1[nt][r] + bb1[nt];                                               \
                e1 = e1 >= 0.f ? e1 : LEAKY * e1;                                               \
                float e2 = acc2[nt][r] + bb2[nt];                                               \
                e2 = e2 >= 0.f ? e2 : LEAKY * e2;                                               \
                float val = e1 + e2;                                                            \
                if (outf) {                                                                     \
                    outf[row * CH + col] = val;                                                 \
                } else {                                                                        \
                    unsigned short h_ = f2bf(val);                                              \
                    xh[row * CH + col] = h_;                                                    \
                    xl[row * CH + col] = f2bf(val - bf2f(h_));                                  \
                }                                                                               \
            }                                                                                   \
        }                                                                                       \
    }

__global__ __launch_bounds__(256, 2) void gemm_mfma(
    unsigned short* xh, unsigned short* xl,
    const unsigned short* __restrict__ aggb,
    const unsigned short* __restrict__ w1bf, const unsigned short* __restrict__ w2bf,
    const float* __restrict__ b1, const float* __restrict__ b2,
    float* outf) {
    const int tid = threadIdx.x;
    const int w = tid >> 6;
    const int lane = tid & 63;
    const int l16 = lane & 15;
    const int khi = (lane >> 4) * 8;

    // weight B-fragments: loaded once, register-resident
    bf16x8 bW1[2][4], bWa[2][4], bWb[2][4];
    float bb1[2], bb2[2];
#pragma unroll
    for (int nt = 0; nt < 2; ++nt) {
        int j = w * 32 + nt * 16 + l16;
        bb1[nt] = b1[j];
        bb2[nt] = b2[j];
#pragma unroll
        for (int kst = 0; kst < 4; ++kst) {
            int kk = kst * 32 + khi;
            bW1[nt][kst] = *(const bf16x8*)&w1bf[j * CH + kk];
            bWa[nt][kst] = *(const bf16x8*)&w2bf[j * 2 * CH + kk];
            bWb[nt][kst] = *(const bf16x8*)&w2bf[j * 2 * CH + CH + kk];
        }
    }

    bf16x8 rhA[4], rlA[4], avA[4], rhB[4], rlB[4], avB[4];
    int strip = blockIdx.x;
    LOADA(rhA, rlA, avA, strip)
    while (true) {
        int nxt = strip + GEMM_BLOCKS;
        if (nxt < NSTRIP) LOADA(rhB, rlB, avB, nxt)
        COMPUTE(rhA, rlA, avA, strip)
        strip = nxt;
        if (strip >= NSTRIP) break;
        nxt = strip + GEMM_BLOCKS;
        if (nxt < NSTRIP) LOADA(rhA, rlA, avA, nxt)
        COMPUTE(rhB, rlB, avB, strip)
        strip = nxt;
        if (strip >= NSTRIP) break;
    }
}

// ---------------- copy weight to second output ------------------------------
__global__ __launch_bounds__(256) void copyw_kernel(const float* __restrict__ w,
                                                    float* __restrict__ out) {
    int i = blockIdx.x * 256 + threadIdx.x;
    if (i < 32 * CH) out[i] = w[i];
}

extern "C" void kernel_launch(void* const* d_in, const int* in_sizes, int n_in,
                              void* d_out, int out_size, void* d_ws, size_t ws_size,
                              hipStream_t stream) {
    const float* emb = (const float*)d_in[0];
    const int* eidx = (const int*)d_in[1];   // int inputs arrive as int32
    const int* etype = (const int*)d_in[2];
    const float* weight = (const float*)d_in[3];
    const float* W1w = (const float*)d_in[4];
    const float* W1b = (const float*)d_in[5];
    const float* W2w = (const float*)d_in[6];
    const float* W2b = (const float*)d_in[7];

    float* out = (float*)d_out;
    float* wout = out + (size_t)N_ENT * CH;   // [32][CH]

    // workspace layout (~41.7 MB)
    char* ws = (char*)d_ws;
    unsigned short* x_hi = (unsigned short*)ws;  ws += (size_t)N_ENT * CH * 2;  // 12.8 MB
    unsigned short* x_lo = (unsigned short*)ws;  ws += (size_t)N_ENT * CH * 2;  // 12.8 MB
    unsigned short* aggb = (unsigned short*)ws;  ws += (size_t)N_ENT * CH * 2;  // 12.8 MB
    unsigned short* w1bf = (unsigned short*)ws;  ws += 2 * CH * CH * 2;         // 64 KB
    unsigned short* w2bf = (unsigned short*)ws;  ws += 2 * CH * 2 * CH * 2;     // 128 KB
    int* packed = (int*)ws;                      ws += (size_t)N_EDG * 4;       // 2.4 MB
    int* offs = (int*)ws;                        ws += (size_t)(N_ENT + 1) * 4;
    int* cursors = (int*)ws;                     ws += (size_t)N_ENT * 4;
    int* counts = (int*)ws;                      ws += (size_t)N_ENT * 4;
    int* bsum = (int*)ws;                        ws += 64 * 4;

    const int* head = eidx;
    const int* tail = eidx + N_EDG;

    // ---- one-time prep: CSR + bf16 operand planes ----
    hipMemsetAsync(counts, 0, N_ENT * sizeof(int), stream);
    count_kernel<<<(N_EDG + 255) / 256, 256, 0, stream>>>(head, counts);
    scan_block<<<NB_SCAN, 256, 0, stream>>>(counts, offs, bsum);
    scan_tops<<<1, 64, 0, stream>>>(bsum);
    add_base<<<NB_SCAN, 256, 0, stream>>>(offs, cursors, bsum);
    fill_kernel<<<(N_EDG + 255) / 256, 256, 0, stream>>>(head, tail, etype, cursors, packed);
    cvt_split_kernel<<<N_ENT * CH / 4 / 256, 256, 0, stream>>>(emb, x_hi, x_lo);
    cvt_w_kernel<<<96, 256, 0, stream>>>(W1w, W2w, w1bf, w2bf);

    // ---- 2 hops ----
    for (int hop = 0; hop < 2; ++hop) {
        agg_kernel<<<N_ENT / 4, 256, 0, stream>>>(x_hi, offs, packed, weight, aggb);
        gemm_mfma<<<GEMM_BLOCKS, 256, 0, stream>>>(
            x_hi, x_lo, aggb, w1bf + hop * CH * CH, w2bf + hop * CH * 2 * CH,
            W1b + hop * CH, W2b + hop * CH,
            hop == 1 ? out : (float*)nullptr);
    }
    copyw_kernel<<<16, 256, 0, stream>>>(weight, wout);
}

// Round 8
// 215.546 us; speedup vs baseline: 12.0207x; 1.1067x over previous
//
#include <hip/hip_runtime.h>
#include <hip/hip_bf16.h>

#define N_ENT 50000
#define N_EDG 600000
#define CH 128
#define LEAKY 0.01f
#define NB_SCAN 49
#define NSTRIP 3125     // 50000 / 16
#define HOP_BLOCKS 625  // 5 strips per block, exact
#define WS_STRIDE 132   // rel-weight LDS row stride (f32): 16B-aligned, bank-spread

typedef __attribute__((ext_vector_type(8))) short bf16x8;
typedef __attribute__((ext_vector_type(4))) float f32x4;

__device__ inline unsigned short f2bf(float x) {
    return __builtin_bit_cast(unsigned short, __float2bfloat16(x));
}
__device__ inline float bflo(unsigned u) { return __builtin_bit_cast(float, u << 16); }
__device__ inline float bfhi(unsigned u) { return __builtin_bit_cast(float, u & 0xFFFF0000u); }

// ---------------- CSR build step 1: in-degree counts ------------------------
__global__ __launch_bounds__(256) void count_kernel(const int* __restrict__ head,
                                                    int* __restrict__ counts) {
    int e = blockIdx.x * 256 + threadIdx.x;
    if (e < N_EDG) atomicAdd(&counts[head[e]], 1);
}

// ---------------- CSR step 2a: per-1024-chunk exclusive scan ----------------
__global__ __launch_bounds__(256) void scan_block(const int* __restrict__ counts,
                                                  int* __restrict__ offs,
                                                  int* __restrict__ bsum) {
    __shared__ int s[256];
    int t = threadIdx.x;
    int base = blockIdx.x * 1024 + t * 4;
    int v[4];
#pragma unroll
    for (int i = 0; i < 4; ++i) {
        int idx = base + i;
        v[i] = (idx < N_ENT) ? counts[idx] : 0;
    }
    int tot = v[0] + v[1] + v[2] + v[3];
    s[t] = tot;
    for (int off = 1; off < 256; off <<= 1) {
        __syncthreads();
        int x = (t >= off) ? s[t - off] : 0;
        __syncthreads();
        s[t] += x;
    }
    int run = s[t] - tot;
#pragma unroll
    for (int i = 0; i < 4; ++i) {
        if (base + i < N_ENT) offs[base + i] = run;
        run += v[i];
    }
    if (t == 255) bsum[blockIdx.x] = s[255];
}

// ---------------- CSR step 2b: scan the 49 chunk totals ----------------------
__global__ __launch_bounds__(64) void scan_tops(int* __restrict__ bsum) {
    int lane = threadIdx.x;
    int v = (lane < NB_SCAN) ? bsum[lane] : 0;
    int orig = v;
#pragma unroll
    for (int off = 1; off < 64; off <<= 1) {
        int x = __shfl_up(v, off);
        if (lane >= off) v += x;
    }
    if (lane < NB_SCAN) bsum[lane] = v - orig;
}

// ---------------- CSR step 2c: add chunk base, init cursors ------------------
__global__ __launch_bounds__(256) void add_base(int* __restrict__ offs,
                                                int* __restrict__ cursors,
                                                const int* __restrict__ bsum) {
    int t = threadIdx.x;
    int base = blockIdx.x * 1024 + t * 4;
    int b = bsum[blockIdx.x];
#pragma unroll
    for (int i = 0; i < 4; ++i) {
        int idx = base + i;
        if (idx < N_ENT) {
            int o = offs[idx] + b;
            offs[idx] = o;
            cursors[idx] = o;
        }
    }
    if (blockIdx.x == 0 && t == 0) offs[N_ENT] = N_EDG;
}

// ---------------- CSR step 3: fill packed edge payloads ----------------------
__global__ __launch_bounds__(256) void fill_kernel(const int* __restrict__ head,
                                                   const int* __restrict__ tail,
                                                   const int* __restrict__ etype,
                                                   int* __restrict__ cursors,
                                                   int* __restrict__ packed) {
    int e = blockIdx.x * 256 + threadIdx.x;
    if (e >= N_EDG) return;
    int h = head[e];
    int pos = atomicAdd(&cursors[h], 1);
    packed[pos] = tail[e] | (etype[e] << 20);
}

// ---------------- one-time conversions: x->bf16, weights->bf16, weight copy --
__global__ __launch_bounds__(256) void prep_cvt(const float* __restrict__ emb,
                                                const float* __restrict__ W1,
                                                const float* __restrict__ W2,
                                                const float* __restrict__ wsrc,
                                                unsigned short* __restrict__ xh,
                                                unsigned short* __restrict__ w1bf,
                                                unsigned short* __restrict__ w2bf,
                                                float* __restrict__ wout) {
    long long gid = (long long)blockIdx.x * 256 + threadIdx.x;  // float4 units
    const long long n_x = (long long)N_ENT * CH / 4;   // 1,600,000
    const long long n_w1 = 2 * CH * CH / 4;            // 8,192
    const long long n_w2 = 2 * CH * 2 * CH / 4;        // 16,384
    // total with copyw: 1,625,600 = 6350 * 256 exactly
    if (gid < n_x) {
        long long k = gid * 4;
        float4 v = *(const float4*)&emb[k];
        ushort4 o;
        o.x = f2bf(v.x); o.y = f2bf(v.y); o.z = f2bf(v.z); o.w = f2bf(v.w);
        *(ushort4*)&xh[k] = o;
    } else if (gid < n_x + n_w1) {
        long long k = (gid - n_x) * 4;
        float4 v = *(const float4*)&W1[k];
        ushort4 o;
        o.x = f2bf(v.x); o.y = f2bf(v.y); o.z = f2bf(v.z); o.w = f2bf(v.w);
        *(ushort4*)&w1bf[k] = o;
    } else if (gid < n_x + n_w1 + n_w2) {
        long long k = (gid - n_x - n_w1) * 4;
        float4 v = *(const float4*)&W2[k];
        ushort4 o;
        o.x = f2bf(v.x); o.y = f2bf(v.y); o.z = f2bf(v.z); o.w = f2bf(v.w);
        *(ushort4*)&w2bf[k] = o;
    } else {
        long long k = (gid - n_x - n_w1 - n_w2) * 4;  // < 1024*4
        *(float4*)&wout[k] = *(const float4*)&wsrc[k];
    }
}

// ---------------- fused hop: aggregate+normalize -> LDS -> dual-GEMM ---------
// Block: 512 threads = 8 waves; strip = 16 rows.
// agg phase: wave w owns rows {2w, 2w+1}; lane = 2 channels; 8 outstanding
//   gathers (2 rows x 4-edge unroll); result (bf16) -> LDS ags[16][136].
// gemm phase: wave w owns cols [16w,16w+16); B-frags (12 = 48 VGPR) persist
//   in registers across all strips; A = xin (global, bf16) + ags (LDS).
// hop1: xout=bf16 plane (ping-pong buffer). hop2: outf=f32 d_out.
__global__ __launch_bounds__(512) void hop_kernel(
    const unsigned short* __restrict__ xin, const int* __restrict__ offs,
    const int* __restrict__ packed, const float* __restrict__ rw,
    const unsigned short* __restrict__ w1bf, const unsigned short* __restrict__ w2bf,
    const float* __restrict__ b1, const float* __restrict__ b2,
    unsigned short* __restrict__ xout, float* __restrict__ outf) {
    __shared__ float ws_[32 * WS_STRIDE];                       // 16.5 KB rel weights
    __shared__ __align__(16) unsigned short ags[16][CH + 8];    // 4.25 KB agg tile

    const int tid = threadIdx.x;
    const int w = tid >> 6;
    const int lane = tid & 63;
    const int l16 = lane & 15;
    const int khi = (lane >> 4) * 8;
    const int c2 = lane * 2;

    // stage relation weights (strided rows, bank-spread)
    {
        int r = tid >> 4;            // 0..31
        int c = (tid & 15) * 8;      // 0..120
        *(float4*)&ws_[r * WS_STRIDE + c] = *(const float4*)&rw[r * CH + c];
        *(float4*)&ws_[r * WS_STRIDE + c + 4] = *(const float4*)&rw[r * CH + c + 4];
    }

    // per-wave weight B-fragments (block-persistent, 48 VGPR)
    bf16x8 bW1[4], bWa[4], bWb[4];
    const int j = w * 16 + l16;
    const float bb1 = b1[j];
    const float bb2 = b2[j];
#pragma unroll
    for (int kst = 0; kst < 4; ++kst) {
        int kk = kst * 32 + khi;
        bW1[kst] = *(const bf16x8*)&w1bf[j * CH + kk];
        bWa[kst] = *(const bf16x8*)&w2bf[j * 2 * CH + kk];
        bWb[kst] = *(const bf16x8*)&w2bf[j * 2 * CH + CH + kk];
    }
    __syncthreads();

    for (int strip = blockIdx.x; strip < NSTRIP; strip += HOP_BLOCKS) {
        const int row0 = strip * 16;

        // ---------------- agg phase ----------------
        int gr = row0 + w * 2;
        int beg0 = offs[gr], mid = offs[gr + 1], end1 = offs[gr + 2];
        int d0 = mid - beg0, d1 = end1 - mid;
        float2 A0 = {0.f, 0.f}, A1 = {0.f, 0.f};
        int dm = max(d0, d1);
        for (int cb = 0; cb < dm; cb += 64) {
            int myp0 = (beg0 + cb + lane < mid) ? packed[beg0 + cb + lane] : 0;
            int myp1 = (mid + cb + lane < end1) ? packed[mid + cb + lane] : 0;
            int n0 = d0 - cb;
            int n1 = d1 - cb;
            int nm = min(max(n0, n1), 64);
            for (int i = 0; i < nm; i += 4) {
                unsigned v[8];
                float2 wv[8];
#pragma unroll
                for (int k = 0; k < 4; ++k) {
                    int p = __shfl(myp0, min(i + k, 63));
                    v[k] = *(const unsigned*)&xin[(long long)(p & 0xFFFFF) * CH + c2];
                    float2 t = *(const float2*)&ws_[(p >> 20) * WS_STRIDE + c2];
                    bool ok = (i + k) < n0;
                    wv[k].x = ok ? t.x : 0.f;
                    wv[k].y = ok ? t.y : 0.f;
                }
#pragma unroll
                for (int k = 0; k < 4; ++k) {
                    int p = __shfl(myp1, min(i + k, 63));
                    v[4 + k] = *(const unsigned*)&xin[(long long)(p & 0xFFFFF) * CH + c2];
                    float2 t = *(const float2*)&ws_[(p >> 20) * WS_STRIDE + c2];
                    bool ok = (i + k) < n1;
                    wv[4 + k].x = ok ? t.x : 0.f;
                    wv[4 + k].y = ok ? t.y : 0.f;
                }
#pragma unroll
                for (int k = 0; k < 4; ++k) {
                    A0.x = fmaf(bflo(v[k]), wv[k].x, A0.x);
                    A0.y = fmaf(bfhi(v[k]), wv[k].y, A0.y);
                    A1.x = fmaf(bflo(v[4 + k]), wv[4 + k].x, A1.x);
                    A1.y = fmaf(bfhi(v[4 + k]), wv[4 + k].y, A1.y);
                }
            }
        }
        float dd0 = fmaxf((float)d0, 1.f), dd1 = fmaxf((float)d1, 1.f);
        A0.x /= dd0; A0.y /= dd0;
        A1.x /= dd1; A1.y /= dd1;
        float s0 = A0.x * A0.x + A0.y * A0.y;
        float s1 = A1.x * A1.x + A1.y * A1.y;
#pragma unroll
        for (int off = 32; off >= 1; off >>= 1) {
            s0 += __shfl_xor(s0, off);
            s1 += __shfl_xor(s1, off);
        }
        float i0 = 1.f / fmaxf(sqrtf(s0), 1e-12f);
        float i1 = 1.f / fmaxf(sqrtf(s1), 1e-12f);
        ushort2 o0, o1;
        o0.x = f2bf(A0.x * i0); o0.y = f2bf(A0.y * i0);
        o1.x = f2bf(A1.x * i1); o1.y = f2bf(A1.y * i1);
        *(ushort2*)&ags[w * 2][c2] = o0;
        *(ushort2*)&ags[w * 2 + 1][c2] = o1;
        __syncthreads();

        // ---------------- gemm phase ----------------
        f32x4 acc1 = {0.f, 0.f, 0.f, 0.f};
        f32x4 acc2 = {0.f, 0.f, 0.f, 0.f};
        long long abase = (long long)(row0 + l16) * CH + khi;
#pragma unroll
        for (int kst = 0; kst < 4; ++kst) {
            bf16x8 rh = *(const bf16x8*)&xin[abase + kst * 32];
            bf16x8 av = *(const bf16x8*)&ags[l16][kst * 32 + khi];
            acc1 = __builtin_amdgcn_mfma_f32_16x16x32_bf16(rh, bW1[kst], acc1, 0, 0, 0);
            acc1 = __builtin_amdgcn_mfma_f32_16x16x32_bf16(av, bW1[kst], acc1, 0, 0, 0);
            acc2 = __builtin_amdgcn_mfma_f32_16x16x32_bf16(rh, bWa[kst], acc2, 0, 0, 0);
            acc2 = __builtin_amdgcn_mfma_f32_16x16x32_bf16(av, bWb[kst], acc2, 0, 0, 0);
        }
#pragma unroll
        for (int r = 0; r < 4; ++r) {
            long long row = row0 + (lane >> 4) * 4 + r;
            float e1 = acc1[r] + bb1;
            e1 = e1 >= 0.f ? e1 : LEAKY * e1;
            float e2 = acc2[r] + bb2;
            e2 = e2 >= 0.f ? e2 : LEAKY * e2;
            float val = e1 + e2;
            if (outf)
                outf[row * CH + j] = val;
            else
                xout[row * CH + j] = f2bf(val);
        }
        __syncthreads();  // ags reused next strip
    }
}

extern "C" void kernel_launch(void* const* d_in, const int* in_sizes, int n_in,
                              void* d_out, int out_size, void* d_ws, size_t ws_size,
                              hipStream_t stream) {
    const float* emb = (const float*)d_in[0];
    const int* eidx = (const int*)d_in[1];   // int inputs arrive as int32
    const int* etype = (const int*)d_in[2];
    const float* weight = (const float*)d_in[3];
    const float* W1w = (const float*)d_in[4];
    const float* W1b = (const float*)d_in[5];
    const float* W2w = (const float*)d_in[6];
    const float* W2b = (const float*)d_in[7];

    float* out = (float*)d_out;
    float* wout = out + (size_t)N_ENT * CH;   // [32][CH]

    // workspace layout (~28.9 MB, proven fits)
    char* ws = (char*)d_ws;
    unsigned short* xh = (unsigned short*)ws;    ws += (size_t)N_ENT * CH * 2;  // 12.8 MB
    unsigned short* xh2 = (unsigned short*)ws;   ws += (size_t)N_ENT * CH * 2;  // 12.8 MB
    unsigned short* w1bf = (unsigned short*)ws;  ws += 2 * CH * CH * 2;         // 64 KB
    unsigned short* w2bf = (unsigned short*)ws;  ws += 2 * CH * 2 * CH * 2;     // 128 KB
    int* packed = (int*)ws;                      ws += (size_t)N_EDG * 4;       // 2.4 MB
    int* offs = (int*)ws;                        ws += (size_t)(N_ENT + 1) * 4;
    int* cursors = (int*)ws;                     ws += (size_t)N_ENT * 4;
    int* counts = (int*)ws;                      ws += (size_t)N_ENT * 4;
    int* bsum = (int*)ws;                        ws += 64 * 4;

    const int* head = eidx;
    const int* tail = eidx + N_EDG;

    // ---- one-time prep: CSR + bf16 operand planes (+ weight output copy) ----
    hipMemsetAsync(counts, 0, N_ENT * sizeof(int), stream);
    count_kernel<<<(N_EDG + 255) / 256, 256, 0, stream>>>(head, counts);
    scan_block<<<NB_SCAN, 256, 0, stream>>>(counts, offs, bsum);
    scan_tops<<<1, 64, 0, stream>>>(bsum);
    add_base<<<NB_SCAN, 256, 0, stream>>>(offs, cursors, bsum);
    fill_kernel<<<(N_EDG + 255) / 256, 256, 0, stream>>>(head, tail, etype, cursors, packed);
    prep_cvt<<<6350, 256, 0, stream>>>(emb, W1w, W2w, weight, xh, w1bf, w2bf, wout);

    // ---- 2 fused hops (ping-pong: xh -> xh2 -> d_out) ----
    hop_kernel<<<HOP_BLOCKS, 512, 0, stream>>>(
        xh, offs, packed, weight, w1bf, w2bf, W1b, W2b, xh2, (float*)nullptr);
    hop_kernel<<<HOP_BLOCKS, 512, 0, stream>>>(
        xh2, offs, packed, weight, w1bf + CH * CH, w2bf + CH * 2 * CH,
        W1b + CH, W2b + CH, (unsigned short*)nullptr, out);
}